// Round 10
// baseline (162.142 us; speedup 1.0000x reference)
//
#include <hip/hip_runtime.h>
#include <hip/hip_bf16.h>

typedef float f32x4_t __attribute__((ext_vector_type(4)));
typedef short bf16x8_t __attribute__((ext_vector_type(8)));

#define MFMA(a, b, c) __builtin_amdgcn_mfma_f32_16x16x32_bf16(a, b, c, 0, 0, 0)

// consts layout offsets (floats)
#define C_Q0   0      // [4][64] q of token0 per CLS
#define C_S00  256    // [4][4]  score(q0,k_cls)/4 per head
#define C_S02  272    // [4][4]  score(q0,k_sep)/4 per head
#define C_VCLS 288    // [4][64]
#define C_VSEP 544    // [64]

__device__ __forceinline__ short f2bf(float x) {
    return (short)__builtin_bit_cast(unsigned short, __float2bfloat16(x));
}
__device__ __forceinline__ float bf2f(short s) {
    return __builtin_bit_cast(float, ((unsigned)(unsigned short)s) << 16);
}
__device__ __forceinline__ float head_sum16(float v) {
#pragma unroll
    for (int off = 1; off < 16; off <<= 1) v += __shfl_xor(v, off, 64);
    return v;
}

// ---------------- combo prep kernel: weight pre-pack + per-CLS consts + hist/cnt
// blocks [0,136): pack; block 136: consts; blocks [137,137+NCH): hist+cnt.
__global__ void k_prep(const float* __restrict__ Wo, const float* __restrict__ Wqkv,
                       const float* __restrict__ W1, const float* __restrict__ W2,
                       const float* __restrict__ Wm, const float* __restrict__ Wc,
                       const float* __restrict__ bqkv,
                       const float* __restrict__ CLS, const float* __restrict__ SEP,
                       const int* __restrict__ etype, const int* __restrict__ dst,
                       short* __restrict__ Bpack, short* __restrict__ WoP,
                       short* __restrict__ WkvP, short* __restrict__ W1P,
                       short* __restrict__ W2P, short* __restrict__ WcP,
                       float* __restrict__ consts,
                       int* __restrict__ hist, int* __restrict__ cnt, int E)
{
    int bx = blockIdx.x;
    if (bx < 136) {
        int tid = bx * 256 + threadIdx.x;
        short tmp[8];
        if (tid < 32768) {          // Wm: B[k=i*64+j][o] = Wm[(o*64+i)*64+j]
            int u = tid, lane = u & 63, nt = (u >> 6) & 3, kstep = u >> 8;
            int o = nt * 16 + (lane & 15);
            int kb = kstep * 32 + (lane >> 4) * 8;
#pragma unroll
            for (int t = 0; t < 8; t++) { int k = kb + t; tmp[t] = f2bf(Wm[(o * 64 + (k >> 6)) * 64 + (k & 63)]); }
            *(bf16x8_t*)&Bpack[(size_t)u * 8] = *(bf16x8_t*)tmp;
        } else if (tid < 33280) {   // Wo: B[k=c][o] = Wo[o*64+c]
            int u = tid - 32768, lane = u & 63, nt = (u >> 6) & 3, kstep = u >> 8;
            int o = nt * 16 + (lane & 15), kb = kstep * 32 + (lane >> 4) * 8;
#pragma unroll
            for (int t = 0; t < 8; t++) tmp[t] = f2bf(Wo[o * 64 + kb + t]);
            *(bf16x8_t*)&WoP[(size_t)u * 8] = *(bf16x8_t*)tmp;
        } else if (tid < 34304) {   // Wk|Wv
            int u = tid - 33280, lane = u & 63, nt = (u >> 6) & 7, kstep = u >> 9;
            int col = nt * 16 + (lane & 15), kb = kstep * 32 + (lane >> 4) * 8;
            int row = 64 + col;
#pragma unroll
            for (int t = 0; t < 8; t++) tmp[t] = f2bf(Wqkv[row * 64 + kb + t]);
            *(bf16x8_t*)&WkvP[(size_t)u * 8] = *(bf16x8_t*)tmp;
        } else if (tid < 34432) {   // W1
            int u = tid - 34304, lane = u & 63, kstep = u >> 6;
            int f = lane & 15, kb = kstep * 32 + (lane >> 4) * 8;
#pragma unroll
            for (int t = 0; t < 8; t++) tmp[t] = f2bf(W1[f * 64 + kb + t]);
            *(bf16x8_t*)&W1P[(size_t)u * 8] = *(bf16x8_t*)tmp;
        } else if (tid < 34688) {   // W2 (K=32, upper half zero)
            int u = tid - 34432, lane = u & 63, nt = u >> 6;
            int o = nt * 16 + (lane & 15), kb = (lane >> 4) * 8;
#pragma unroll
            for (int t = 0; t < 8; t++) { int k = kb + t; tmp[t] = (k < 16) ? f2bf(W2[o * 16 + k]) : (short)0; }
            *(bf16x8_t*)&W2P[(size_t)u * 8] = *(bf16x8_t*)tmp;
        } else if (tid < 34816) {   // Wc (cols >=4 zero)
            int u = tid - 34688, lane = u & 63, kstep = u >> 6;
            int m = lane & 15, kb = kstep * 32 + (lane >> 4) * 8;
#pragma unroll
            for (int t = 0; t < 8; t++) tmp[t] = (m < 4) ? f2bf(Wc[m * 64 + kb + t]) : (short)0;
            *(bf16x8_t*)&WcP[(size_t)u * 8] = *(bf16x8_t*)tmp;
        }
    } else if (bx == 136) {
        if (threadIdx.x < 64) {
            int lane = threadIdx.x;
            float ksep = bqkv[64 + lane], vsep = bqkv[128 + lane];
            for (int c = 0; c < 64; c++) {
                float sc = SEP[c];
                ksep += Wqkv[(64 + lane) * 64 + c] * sc;
                vsep += Wqkv[(128 + lane) * 64 + c] * sc;
            }
            consts[C_VSEP + lane] = vsep;
            for (int i = 0; i < 4; i++) {
                float q0 = bqkv[lane], kcls = bqkv[64 + lane], vcls = bqkv[128 + lane];
                for (int c = 0; c < 64; c++) {
                    float cc = CLS[i * 64 + c];
                    q0   += Wqkv[lane * 64 + c] * cc;
                    kcls += Wqkv[(64 + lane) * 64 + c] * cc;
                    vcls += Wqkv[(128 + lane) * 64 + c] * cc;
                }
                consts[C_Q0 + i * 64 + lane] = q0;
                consts[C_VCLS + i * 64 + lane] = vcls;
                float p00 = head_sum16(q0 * kcls) * 0.25f;
                float p02 = head_sum16(q0 * ksep) * 0.25f;
                if ((lane & 15) == 0) {
                    consts[C_S00 + i * 4 + (lane >> 4)] = p00;
                    consts[C_S02 + i * 4 + (lane >> 4)] = p02;
                }
            }
        }
    } else {
        __shared__ int h[8];
        int chunk = bx - 137;
        int tid = threadIdx.x;
        if (tid < 8) h[tid] = 0;
        __syncthreads();
        int e = chunk * 256 + tid;
        if (e < E) {
            atomicAdd(&h[etype[e]], 1);
            atomicAdd(&cnt[dst[e]], 1);
        }
        __syncthreads();
        if (tid < 8) hist[chunk * 8 + tid] = h[tid];
    }
}

// ---------------- scan (1 block, 64 lanes) + pack score-projection Wqk
__global__ void k_scan(const int* __restrict__ hist, int* __restrict__ chunkoff,
                       int* __restrict__ startg, int* __restrict__ countsg, int nch,
                       const float* __restrict__ consts, const float* __restrict__ Wqkv,
                       const float* __restrict__ bqkv,
                       short* __restrict__ WqkP, float* __restrict__ bqk)
{
    int lane = threadIdx.x;          // 64: lane = seg*8 + g
    int g = lane & 7, seg = lane >> 3;
    int per = (nch + 7) / 8;
    int c0 = seg * per, c1 = c0 + per; if (c1 > nch) c1 = nch;
    int sum = 0;
    for (int c = c0; c < c1; c++) sum += hist[c * 8 + g];
    int pre = 0, tot = 0;
#pragma unroll
    for (int s2 = 0; s2 < 8; s2++) {
        int v = __shfl(sum, s2 * 8 + g, 64);
        tot += v;
        if (s2 < seg) pre += v;
    }
    int run = pre;
    for (int c = c0; c < c1; c++) { chunkoff[c * 8 + g] = run; run += hist[c * 8 + g]; }
    if (seg == 0) {
        countsg[g] = tot;
        int sg = 0;
#pragma unroll
        for (int g2 = 0; g2 < 8; g2++) { int v = __shfl(tot, g2, 64); if (g2 < g) sg += v; }
        startg[g] = sg;
    }

    // ---- Wqk pack: frag P[(kstep*64+lane)*8+t] = Wqk[lane&15][kstep*32+(lane>>4)*8+t]
    int ih = lane & 15, ii = ih & 3, hh = ih >> 2;
    int lh8 = (lane >> 4) * 8;
    short tmp[8];
#pragma unroll
    for (int kstep = 0; kstep < 2; kstep++) {
#pragma unroll
        for (int t = 0; t < 8; t++) {
            int k = kstep * 32 + lh8 + t;
            float s = 0.f;
            for (int u = 0; u < 16; u++)
                s += consts[C_Q0 + ii * 64 + hh * 16 + u] * Wqkv[(64 + hh * 16 + u) * 64 + k];
            tmp[t] = f2bf(0.25f * s);
        }
        *(bf16x8_t*)&WqkP[(size_t)(kstep * 64 + lane) * 8] = *(bf16x8_t*)tmp;
    }
    if (lane < 16) {
        float s = 0.f;
        for (int u = 0; u < 16; u++)
            s += consts[C_Q0 + ii * 64 + hh * 16 + u] * bqkv[64 + hh * 16 + u];
        bqk[lane] = 0.25f * s;
    }
}

// ---------------- v-projection + per-node attention scores qs via MFMA: 64 nodes/block
__global__ __launch_bounds__(256) void k_kv(const float* __restrict__ feat,
        const short* __restrict__ WkvP, const short* __restrict__ WqkP,
        const float* __restrict__ bqkv, const float* __restrict__ bqk,
        float* __restrict__ vnode, float* __restrict__ qs, int N)
{
    __shared__ __align__(16) short sA[64 * 72];
    int tid = threadIdx.x, lane = tid & 63, w = tid >> 6;
    int l15 = lane & 15, lh = lane >> 4;
    int base = blockIdx.x * 64;
#pragma unroll
    for (int rr = 0; rr < 16; rr++) {
        int row = w * 16 + rr;
        int n = base + row; n = n < N ? n : N - 1;
        sA[row * 72 + lane] = f2bf(feat[(size_t)n * 64 + lane]);
    }
    __syncthreads();
    const bf16x8_t* bp = (const bf16x8_t*)WkvP;
    bf16x8_t bv0 = bp[(0 * 8 + 4 + w) * 64 + lane];
    bf16x8_t bv1 = bp[(1 * 8 + 4 + w) * 64 + lane];
    bf16x8_t bq0 = ((const bf16x8_t*)WqkP)[lane];
    bf16x8_t bq1 = ((const bf16x8_t*)WqkP)[64 + lane];
    int kof = lh * 8;
    int col = w * 16 + l15;
    float biasv = bqkv[128 + col];
    float bqv = bqk[l15];
#pragma unroll
    for (int rt = 0; rt < 4; rt++) {
        bf16x8_t a0 = *(const bf16x8_t*)&sA[(rt * 16 + l15) * 72 + kof];
        bf16x8_t a1 = *(const bf16x8_t*)&sA[(rt * 16 + l15) * 72 + 32 + kof];
        f32x4_t av = {0.f, 0.f, 0.f, 0.f};
        av = MFMA(a0, bv0, av); av = MFMA(a1, bv1, av);
#pragma unroll
        for (int r = 0; r < 4; r++) {
            int n = base + rt * 16 + lh * 4 + r;
            if (n < N) vnode[(size_t)n * 64 + col] = av[r] + biasv;
        }
        if (w == 0) {
            f32x4_t aq = {0.f, 0.f, 0.f, 0.f};
            aq = MFMA(a0, bq0, aq); aq = MFMA(a1, bq1, aq);
#pragma unroll
            for (int r = 0; r < 4; r++) {
                int n = base + rt * 16 + lh * 4 + r;
                if (n < N) qs[(size_t)n * 16 + l15] = aq[r] + bqv;
            }
        }
    }
}

struct EncW {
    const float* consts; const float* CLS; const float* bo;
    const float* b1; const float* b2;
    const float* ln1w; const float* ln1b; const float* ln2w; const float* ln2b;
    const short* WoP; const short* W1P; const short* W2P; const short* WcP;
    const float* bc;
};

// ---------------- batched encoder: 16 units x 4 CLS = 64 rows per block.
__global__ __launch_bounds__(256) void k_enc(const int* __restrict__ src_idx,
        const int* __restrict__ dst_idx,
        const float* __restrict__ vnode, const float* __restrict__ qs, EncW W,
        float* __restrict__ mem_out, float* __restrict__ cat_out, int E, int M)
{
    __shared__ __align__(16) short sA[64 * 72];   // att -> y -> t (wave-private rows)
    __shared__ __align__(16) short sF[64 * 40];   // ff, k=16..31 zero-padded
    int tid = threadIdx.x, lane = tid & 63, w = tid >> 6;
    int l15 = lane & 15, lh = lane >> 4;
    int base = blockIdx.x * 16;

#pragma unroll
    for (int z = 0; z < 4; z++) {
        int zz = z * 64 + lane;
        sF[(w * 16 + (zz >> 4)) * 40 + 16 + (zz & 15)] = 0;
    }

    float vclsr[4], s00r[4], s02r[4];
#pragma unroll
    for (int i = 0; i < 4; i++) {
        vclsr[i] = W.consts[C_VCLS + i * 64 + lane];
        s00r[i]  = W.consts[C_S00 + i * 4 + lh];
        s02r[i]  = W.consts[C_S02 + i * 4 + lh];
    }
    float vsep = W.consts[C_VSEP + lane];

    // ---- attention phase: scores from qs, v gathers only
#pragma unroll
    for (int el = 0; el < 4; el++) {
        int eloc = w * 4 + el;
        int ge = base + eloc; int gc = ge < M ? ge : M - 1;
        int s, d;
        if (gc < E) { s = src_idx[gc]; d = dst_idx[gc]; }
        else        { s = gc - E; d = s; }
        float vs_ = vnode[(size_t)s * 64 + lane];
        float vd  = vnode[(size_t)d * 64 + lane];
        float4 qh_s = *(const float4*)&qs[(size_t)s * 16 + lh * 4];
        float4 qh_d = *(const float4*)&qs[(size_t)d * 16 + lh * 4];
        float qsv[4] = {qh_s.x, qh_s.y, qh_s.z, qh_s.w};
        float qdv[4] = {qh_d.x, qh_d.y, qh_d.z, qh_d.w};
#pragma unroll
        for (int i = 0; i < 4; i++) {
            float s01 = qsv[i], s03 = qdv[i];
            float s00 = s00r[i], s02 = s02r[i];
            float mx = fmaxf(fmaxf(s00, s01), fmaxf(s02, s03));
            float e0 = __expf(s00 - mx), e1 = __expf(s01 - mx);
            float e2 = __expf(s02 - mx), e3 = __expf(s03 - mx);
            float inv = 1.0f / (e0 + e1 + e2 + e3);
            float att = (e0 * vclsr[i] + e1 * vs_ + e2 * vsep + e3 * vd) * inv;
            sA[(eloc * 4 + i) * 72 + lane] = f2bf(att);
        }
    }

    int arow = (w * 16 + l15) * 72;
    int kof = lh * 8;

    const bf16x8_t* bpo = (const bf16x8_t*)W.WoP;
    f32x4_t ac0 = {0.f,0.f,0.f,0.f}, ac1 = ac0, ac2 = ac0, ac3 = ac0;
#pragma unroll
    for (int kstep = 0; kstep < 2; kstep++) {
        bf16x8_t a = *(const bf16x8_t*)&sA[arow + kstep * 32 + kof];
        ac0 = MFMA(a, bpo[(kstep * 4 + 0) * 64 + lane], ac0);
        ac1 = MFMA(a, bpo[(kstep * 4 + 1) * 64 + lane], ac1);
        ac2 = MFMA(a, bpo[(kstep * 4 + 2) * 64 + lane], ac2);
        ac3 = MFMA(a, bpo[(kstep * 4 + 3) * 64 + lane], ac3);
    }

    float x[4][4], y[4][4];
#pragma unroll
    for (int r = 0; r < 4; r++) { x[0][r] = ac0[r]; x[1][r] = ac1[r]; x[2][r] = ac2[r]; x[3][r] = ac3[r]; }
    float lw1[4], lb1[4];
#pragma unroll
    for (int nt = 0; nt < 4; nt++) {
        float b = W.bo[nt * 16 + l15];
        lw1[nt] = W.ln1w[nt * 16 + l15]; lb1[nt] = W.ln1b[nt * 16 + l15];
#pragma unroll
        for (int r = 0; r < 4; r++) x[nt][r] += b + W.CLS[r * 64 + nt * 16 + l15];
    }
#pragma unroll
    for (int r = 0; r < 4; r++) {
        float sm = head_sum16(x[0][r] + x[1][r] + x[2][r] + x[3][r]);
        float mu = sm * 0.015625f;
        float vv = 0.f;
#pragma unroll
        for (int nt = 0; nt < 4; nt++) { float dd = x[nt][r] - mu; vv = fmaf(dd, dd, vv); }
        vv = head_sum16(vv);
        float rs = rsqrtf(vv * 0.015625f + 1e-5f);
#pragma unroll
        for (int nt = 0; nt < 4; nt++) y[nt][r] = (x[nt][r] - mu) * rs * lw1[nt] + lb1[nt];
    }
#pragma unroll
    for (int nt = 0; nt < 4; nt++)
#pragma unroll
        for (int r = 0; r < 4; r++)
            sA[(w * 16 + lh * 4 + r) * 72 + nt * 16 + l15] = f2bf(y[nt][r]);

    const bf16x8_t* bp1 = (const bf16x8_t*)W.W1P;
    f32x4_t fa = {0.f,0.f,0.f,0.f};
#pragma unroll
    for (int kstep = 0; kstep < 2; kstep++) {
        bf16x8_t a = *(const bf16x8_t*)&sA[arow + kstep * 32 + kof];
        fa = MFMA(a, bp1[kstep * 64 + lane], fa);
    }
    float b1v = W.b1[l15];
#pragma unroll
    for (int r = 0; r < 4; r++)
        sF[(w * 16 + lh * 4 + r) * 40 + l15] = f2bf(fmaxf(fa[r] + b1v, 0.f));

    const bf16x8_t* bp2 = (const bf16x8_t*)W.W2P;
    bf16x8_t af = *(const bf16x8_t*)&sF[(w * 16 + l15) * 40 + kof];
    f32x4_t z0 = {0.f,0.f,0.f,0.f}, z1 = z0, z2 = z0, z3 = z0;
    z0 = MFMA(af, bp2[0 * 64 + lane], z0);
    z1 = MFMA(af, bp2[1 * 64 + lane], z1);
    z2 = MFMA(af, bp2[2 * 64 + lane], z2);
    z3 = MFMA(af, bp2[3 * 64 + lane], z3);

    float t[4][4];
#pragma unroll
    for (int r = 0; r < 4; r++) { x[0][r] = z0[r]; x[1][r] = z1[r]; x[2][r] = z2[r]; x[3][r] = z3[r]; }
    float lw2[4], lb2[4];
#pragma unroll
    for (int nt = 0; nt < 4; nt++) {
        float b = W.b2[nt * 16 + l15];
        lw2[nt] = W.ln2w[nt * 16 + l15]; lb2[nt] = W.ln2b[nt * 16 + l15];
#pragma unroll
        for (int r = 0; r < 4; r++) x[nt][r] += b + y[nt][r];
    }
#pragma unroll
    for (int r = 0; r < 4; r++) {
        float sm = head_sum16(x[0][r] + x[1][r] + x[2][r] + x[3][r]);
        float mu = sm * 0.015625f;
        float vv = 0.f;
#pragma unroll
        for (int nt = 0; nt < 4; nt++) { float dd = x[nt][r] - mu; vv = fmaf(dd, dd, vv); }
        vv = head_sum16(vv);
        float rs = rsqrtf(vv * 0.015625f + 1e-5f);
#pragma unroll
        for (int nt = 0; nt < 4; nt++) t[nt][r] = (x[nt][r] - mu) * rs * lw2[nt] + lb2[nt];
    }

    int eloc = w * 4 + lh, ge = base + eloc;

    if (base < E) {
#pragma unroll
        for (int nt = 0; nt < 4; nt++)
#pragma unroll
            for (int r = 0; r < 4; r++)
                sA[(w * 16 + lh * 4 + r) * 72 + nt * 16 + l15] = f2bf(t[nt][r]);
        const bf16x8_t* bpc = (const bf16x8_t*)W.WcP;
        f32x4_t ca = {0.f,0.f,0.f,0.f};
#pragma unroll
        for (int kstep = 0; kstep < 2; kstep++) {
            bf16x8_t a = *(const bf16x8_t*)&sA[arow + kstep * 32 + kof];
            ca = MFMA(a, bpc[kstep * 64 + lane], ca);
        }
        if (l15 < 4 && ge < E) {
            float bcv = W.bc[l15];
#pragma unroll
            for (int r = 0; r < 4; r++)
                cat_out[((size_t)r * E + ge) * 4 + l15] = ca[r] + bcv;
        }
    }

    if (ge < M) {
#pragma unroll
        for (int nt = 0; nt < 4; nt++)
            mem_out[(size_t)ge * 64 + nt * 16 + l15] = t[nt][0] + t[nt][1] + t[nt][2] + t[nt][3];
    }
}

// ---------------- hypernetwork bilinear v9 "P-scheme", 2x2 wave tiling:
// wave = (row-half rw, col-half cw): 64 rows x 32 cols per wave.
// Same MFMA/fold counts as v7, but B LDS-reads HALVED (only 2 nt per wave).
// xsT is cross-wave-read -> one __syncthreads() before the pipeline (also
// drains chunk 0); in-loop counted vmcnt(4) schedule preserved.
__global__ __launch_bounds__(256, 3) void k_hyper(
        const float* __restrict__ feat, const int* __restrict__ src_idx,
        const int* __restrict__ dst_idx, const float* __restrict__ memall,
        const short* __restrict__ Bpack,
        float* __restrict__ agg, float* __restrict__ selfm, int E, int M)
{
    __shared__ short xsT[64 * 132];                 // bf16 x^T: [i][row]
    __shared__ __align__(16) short sB[2][8192];     // 2 x 16KB: 2-i B-frag chunks
    int tid = threadIdx.x, lane = tid & 63, w = tid >> 6;
    int l15 = lane & 15, lh = lane >> 4, koff = lh * 8;
    int rw = w >> 1, cw = w & 1;
    int base = blockIdx.x * 128;

    const bf16x8_t* bp = (const bf16x8_t*)Bpack;

    auto stage = [&](int c, int buf) {
#pragma unroll
        for (int jj = 0; jj < 4; ++jj) {
            int j = w * 4 + jj;
            int il_ic = j >> 3, q = j & 7;
            const short* src = (const short*)(bp + (size_t)(c * 2 + il_ic) * 512
                                              + (q >> 2) * 256 + (q & 3) * 64 + lane);
            short* dst = &sB[buf][j * 512];
            __builtin_amdgcn_global_load_lds(
                (const __attribute__((address_space(1))) void*)src,
                (__attribute__((address_space(3))) void*)dst, 16, 0, 0);
        }
    };

    stage(0, 0);

    // xsT staging: wave w writes rows w*32..w*32+31 (read cross-wave later)
    for (int rr = 0; rr < 32; ++rr) {
        int row = w * 32 + rr, gr = base + row;
        float xv = 0.f;
        if (gr < M) {
            int xi = gr < E ? src_idx[gr] : gr - E;
            xv = feat[(size_t)xi * 64 + lane];
        }
        xsT[lane * 132 + row] = f2bf(xv);
    }

    // m as CONSTANT bf16 A-frags: 4 row-tiles (this wave's row half) x 2 k-halves
    bf16x8_t am[4][2];
#pragma unroll
    for (int tt = 0; tt < 4; ++tt) {
        int gr = base + rw * 64 + tt * 16 + l15;
        const float* mp = memall + (size_t)(gr < M ? gr : 0) * 64 + koff;
#pragma unroll
        for (int kk = 0; kk < 2; ++kk)
#pragma unroll
            for (int t = 0; t < 8; ++t)
                am[tt][kk][t] = f2bf(mp[kk * 32 + t]);
    }

    f32x4_t out[4][2];   // [row-tile][nt2]
#pragma unroll
    for (int tt = 0; tt < 4; ++tt)
#pragma unroll
        for (int n2 = 0; n2 < 2; ++n2) out[tt][n2] = (f32x4_t){0.f, 0.f, 0.f, 0.f};
    const f32x4_t ZERO = {0.f, 0.f, 0.f, 0.f};

    int xrow0 = rw * 64 + lh * 4;
    int nt0 = cw * 2, nt1 = cw * 2 + 1;

    __syncthreads();   // xsT visible to all waves; chunk 0 drained

    int cur = 0;
    for (int c = 0; c < 32; ++c) {
        if (c + 1 < 32) {
            stage(c + 1, cur ^ 1);
            asm volatile("s_waitcnt vmcnt(4)" ::: "memory");   // chunk c landed; c+1 in flight
        } else {
            asm volatile("s_waitcnt vmcnt(0)" ::: "memory");
        }
        __builtin_amdgcn_s_barrier();
#pragma unroll
        for (int ic = 0; ic < 2; ++ic) {
            int i = c * 2 + ic;
            float xv[4][4];
#pragma unroll
            for (int tt = 0; tt < 4; ++tt) {
                unsigned long long xw = *(const unsigned long long*)&xsT[i * 132 + xrow0 + tt * 16];
                unsigned lo = (unsigned)xw, hi = (unsigned)(xw >> 32);
                xv[tt][0] = __builtin_bit_cast(float, lo << 16);
                xv[tt][1] = __builtin_bit_cast(float, lo & 0xffff0000u);
                xv[tt][2] = __builtin_bit_cast(float, hi << 16);
                xv[tt][3] = __builtin_bit_cast(float, hi & 0xffff0000u);
            }
            const bf16x8_t* bfr = (const bf16x8_t*)&sB[cur][ic * 4096];
            bf16x8_t B00 = bfr[nt0 * 64 + lane];        // kk=0, nt0
            bf16x8_t B01 = bfr[nt1 * 64 + lane];        // kk=0, nt1
            bf16x8_t B10 = bfr[(4 + nt0) * 64 + lane];  // kk=1, nt0
            bf16x8_t B11 = bfr[(4 + nt1) * 64 + lane];  // kk=1, nt1
            f32x4_t P[4][2];
            __builtin_amdgcn_s_setprio(1);
#pragma unroll
            for (int tt = 0; tt < 4; ++tt) {
                P[tt][0] = MFMA(am[tt][0], B00, ZERO);
                P[tt][1] = MFMA(am[tt][0], B01, ZERO);
                P[tt][0] = MFMA(am[tt][1], B10, P[tt][0]);
                P[tt][1] = MFMA(am[tt][1], B11, P[tt][1]);
            }
            __builtin_amdgcn_s_setprio(0);
#pragma unroll
            for (int tt = 0; tt < 4; ++tt)
#pragma unroll
                for (int n2 = 0; n2 < 2; ++n2)
#pragma unroll
                    for (int r = 0; r < 4; ++r)
                        out[tt][n2][r] = fmaf(xv[tt][r], P[tt][n2][r], out[tt][n2][r]);
        }
        __builtin_amdgcn_s_barrier();
        cur ^= 1;
    }

    // C/D: col = lane&15, row = (lane>>4)*4 + reg
#pragma unroll
    for (int tt = 0; tt < 4; ++tt) {
        int orow = rw * 64 + tt * 16 + lh * 4;
        int di[4];
#pragma unroll
        for (int r = 0; r < 4; ++r) {
            int grow = base + orow + r;
            di[r] = (grow < E) ? dst_idx[grow] : 0;
        }
#pragma unroll
        for (int n2 = 0; n2 < 2; ++n2) {
            int o = (cw * 2 + n2) * 16 + l15;
#pragma unroll
            for (int r = 0; r < 4; ++r) {
                int grow = base + orow + r;
                if (grow < M) {
                    float v = out[tt][n2][r];
                    if (grow < E) atomicAdd(&agg[(size_t)di[r] * 64 + o], v);
                    else selfm[(size_t)(grow - E) * 64 + o] = v;
                }
            }
        }
    }
}

// ---------------- finalize + scatter merged: blocks [0,FB) fin, [FB,FB+NCH) scatter
__global__ __launch_bounds__(256) void k_finsc(
        const float* __restrict__ agg, const int* __restrict__ cnt,
        const float* __restrict__ selfm, const float* __restrict__ h_bias,
        float* __restrict__ outp, int N,
        const int* __restrict__ etype, const float* __restrict__ cat_all,
        const int* __restrict__ chunkoff, const int* __restrict__ startg,
        const int* __restrict__ countsg,
        float* __restrict__ out_label, float* __restrict__ out_cat, int E, int FB)
{
    if ((int)blockIdx.x < FB) {
        int t = blockIdx.x * 256 + threadIdx.x;
        if (t < N * 64) {
            int n = t >> 6, o = t & 63;
            int c = cnt[n];
            float av = (c > 0) ? agg[t] / (float)c : 0.f;
            outp[t] = av + h_bias[o] + selfm[t];
        }
    } else {
        __shared__ int wc[4][8];
        int tid = threadIdx.x, lane = tid & 63, w = tid >> 6;
        int chunk = blockIdx.x - FB;
        int e = chunk * 256 + w * 64 + lane;
        int et = (e < E) ? etype[e] : -1;
        unsigned long long mk[8];
#pragma unroll
        for (int g = 0; g < 8; g++) mk[g] = __ballot(et == g);
        if (lane < 8) wc[w][lane] = (int)__popcll(mk[lane]);
        __syncthreads();
        if (et >= 0) {
            unsigned long long lt = (1ull << lane) - 1ull;
            int myr = chunkoff[chunk * 8 + et] + (int)__popcll(mk[et] & lt);
#pragma unroll
            for (int w2 = 0; w2 < 4; w2++) if (w2 < w) myr += wc[w2][et];
            int sg = startg[et], cg = countsg[et];
            size_t pbase = (size_t)sg * 4 + myr;
#pragma unroll
            for (int i = 0; i < 4; i++) {
                size_t pos = pbase + (size_t)i * cg;
                out_label[pos] = (float)i;
                const float* ca = &cat_all[((size_t)i * E + e) * 4];
                float4 cv = {ca[0], ca[1], ca[2], ca[3]};
                *(float4*)&out_cat[pos * 4] = cv;
            }
        }
    }
}

extern "C" void kernel_launch(void* const* d_in, const int* in_sizes, int n_in,
                              void* d_out, int out_size, void* d_ws, size_t ws_size,
                              hipStream_t stream)
{
    const float* feat    = (const float*)d_in[0];
    const int*   src_idx = (const int*)d_in[1];
    const int*   dst_idx = (const int*)d_in[2];
    const int*   etype   = (const int*)d_in[3];
    const float* Wqkv    = (const float*)d_in[4];
    const float* bqkv    = (const float*)d_in[5];
    const float* Wo      = (const float*)d_in[6];
    const float* bo      = (const float*)d_in[7];
    const float* W1      = (const float*)d_in[8];
    const float* b1      = (const float*)d_in[9];
    const float* W2      = (const float*)d_in[10];
    const float* b2      = (const float*)d_in[11];
    const float* ln1w    = (const float*)d_in[12];
    const float* ln1b    = (const float*)d_in[13];
    const float* ln2w    = (const float*)d_in[14];
    const float* ln2b    = (const float*)d_in[15];
    const float* Wc      = (const float*)d_in[16];
    const float* bc      = (const float*)d_in[17];
    const float* CLS     = (const float*)d_in[18];
    const float* SEP     = (const float*)d_in[19];
    const float* Wm      = (const float*)d_in[20];
    const float* h_bias  = (const float*)d_in[21];

    const int N = in_sizes[0] / 64;
    const int E = in_sizes[1];
    const int M = E + N;                 // total hyper/encoder units
    const int NCH = (E + 255) / 256;
    const int FB = (N * 64 + 255) / 256;

    float* ws = (float*)d_ws;
    size_t off = 0;
    auto alloc = [&](size_t n) { float* p = ws + off; off += (n + 63) & ~(size_t)63; return p; };
    float* qs      = alloc((size_t)N * 16);          // per-node attention scores [N][h*4+i]
    float* vnode   = alloc((size_t)N * 64);
    float* mem_all = alloc((size_t)M * 64);          // [0,E) edge, [E,M) self
    float* cat_all = alloc((size_t)E * 16);
    float* agg     = alloc((size_t)N * 64 + N);      // agg + cnt contiguous for one memset
    int*   cnt     = (int*)(agg + (size_t)N * 64);
    float* selfm   = alloc((size_t)N * 64);
    float* consts  = alloc(1024);
    short* Bpack   = (short*)alloc(131072);          // 262144 bf16
    short* WoP     = (short*)alloc(2048);
    short* WkvP    = (short*)alloc(4096);
    short* W1P     = (short*)alloc(512);
    short* W2P     = (short*)alloc(1024);
    short* WcP     = (short*)alloc(512);
    short* WqkP    = (short*)alloc(512);             // 1024 bf16
    float* bqk     = alloc(64);
    int*   hist    = (int*)alloc(NCH * 8);
    int*   chunkoff= (int*)alloc(NCH * 8);
    int*   startg  = (int*)alloc(8);
    int*   countsg = (int*)alloc(8);

    float* out_node  = (float*)d_out;
    float* out_label = out_node + (size_t)N * 64;
    float* out_cat   = out_label + (size_t)4 * E;

    hipMemsetAsync(agg, 0, ((size_t)N * 64 + N) * sizeof(float), stream);

    k_prep<<<137 + NCH, 256, 0, stream>>>(Wo, Wqkv, W1, W2, Wm, Wc, bqkv, CLS, SEP,
                                          etype, dst_idx, Bpack, WoP, WkvP, W1P, W2P, WcP,
                                          consts, hist, cnt, E);
    k_scan<<<1, 64, 0, stream>>>(hist, chunkoff, startg, countsg, NCH,
                                 consts, Wqkv, bqkv, WqkP, bqk);

    k_kv<<<(N + 63) / 64, 256, 0, stream>>>(feat, WkvP, WqkP, bqkv, bqk, vnode, qs, N);

    EncW W{consts, CLS, bo, b1, b2, ln1w, ln1b, ln2w, ln2b, WoP, W1P, W2P, WcP, bc};

    k_enc<<<(M + 15) / 16, 256, 0, stream>>>(src_idx, dst_idx, vnode, qs, W,
                                             mem_all, cat_all, E, M);

    k_hyper<<<(M + 127) / 128, 256, 0, stream>>>(feat, src_idx, dst_idx, mem_all, Bpack,
                                                 agg, selfm, E, M);

    k_finsc<<<FB + NCH, 256, 0, stream>>>(agg, cnt, selfm, h_bias, out_node, N,
                                          etype, cat_all, chunkoff, startg, countsg,
                                          out_label, out_cat, E, FB);
}

// Round 11
// 147.234 us; speedup vs baseline: 1.1012x; 1.1012x over previous
//
#include <hip/hip_runtime.h>
#include <hip/hip_bf16.h>

typedef float f32x4_t __attribute__((ext_vector_type(4)));
typedef short bf16x8_t __attribute__((ext_vector_type(8)));

#define MFMA(a, b, c) __builtin_amdgcn_mfma_f32_16x16x32_bf16(a, b, c, 0, 0, 0)

// consts layout offsets (floats)
#define C_Q0   0      // [4][64] q of token0 per CLS
#define C_S00  256    // [4][4]  score(q0,k_cls)/4 per head
#define C_S02  272    // [4][4]  score(q0,k_sep)/4 per head
#define C_VCLS 288    // [4][64]
#define C_VSEP 544    // [64]

__device__ __forceinline__ short f2bf(float x) {
    return (short)__builtin_bit_cast(unsigned short, __float2bfloat16(x));
}
__device__ __forceinline__ float bf2f(short s) {
    return __builtin_bit_cast(float, ((unsigned)(unsigned short)s) << 16);
}
__device__ __forceinline__ float head_sum16(float v) {
#pragma unroll
    for (int off = 1; off < 16; off <<= 1) v += __shfl_xor(v, off, 64);
    return v;
}

// ---------------- combo prep kernel: weight pre-pack + per-CLS consts + hist/cnt
// blocks [0,136): pack; block 136: consts; blocks [137,137+NCH): hist+cnt.
__global__ void k_prep(const float* __restrict__ Wo, const float* __restrict__ Wqkv,
                       const float* __restrict__ W1, const float* __restrict__ W2,
                       const float* __restrict__ Wm, const float* __restrict__ Wc,
                       const float* __restrict__ bqkv,
                       const float* __restrict__ CLS, const float* __restrict__ SEP,
                       const int* __restrict__ etype, const int* __restrict__ dst,
                       short* __restrict__ Bpack, short* __restrict__ WoP,
                       short* __restrict__ WkvP, short* __restrict__ W1P,
                       short* __restrict__ W2P, short* __restrict__ WcP,
                       float* __restrict__ consts,
                       int* __restrict__ hist, int* __restrict__ cnt, int E)
{
    int bx = blockIdx.x;
    if (bx < 136) {
        int tid = bx * 256 + threadIdx.x;
        short tmp[8];
        if (tid < 32768) {          // Wm: B[k=i*64+j][o] = Wm[(o*64+i)*64+j]
            int u = tid, lane = u & 63, nt = (u >> 6) & 3, kstep = u >> 8;
            int o = nt * 16 + (lane & 15);
            int kb = kstep * 32 + (lane >> 4) * 8;
#pragma unroll
            for (int t = 0; t < 8; t++) { int k = kb + t; tmp[t] = f2bf(Wm[(o * 64 + (k >> 6)) * 64 + (k & 63)]); }
            *(bf16x8_t*)&Bpack[(size_t)u * 8] = *(bf16x8_t*)tmp;
        } else if (tid < 33280) {   // Wo: B[k=c][o] = Wo[o*64+c]
            int u = tid - 32768, lane = u & 63, nt = (u >> 6) & 3, kstep = u >> 8;
            int o = nt * 16 + (lane & 15), kb = kstep * 32 + (lane >> 4) * 8;
#pragma unroll
            for (int t = 0; t < 8; t++) tmp[t] = f2bf(Wo[o * 64 + kb + t]);
            *(bf16x8_t*)&WoP[(size_t)u * 8] = *(bf16x8_t*)tmp;
        } else if (tid < 34304) {   // Wk|Wv
            int u = tid - 33280, lane = u & 63, nt = (u >> 6) & 7, kstep = u >> 9;
            int col = nt * 16 + (lane & 15), kb = kstep * 32 + (lane >> 4) * 8;
            int row = 64 + col;
#pragma unroll
            for (int t = 0; t < 8; t++) tmp[t] = f2bf(Wqkv[row * 64 + kb + t]);
            *(bf16x8_t*)&WkvP[(size_t)u * 8] = *(bf16x8_t*)tmp;
        } else if (tid < 34432) {   // W1
            int u = tid - 34304, lane = u & 63, kstep = u >> 6;
            int f = lane & 15, kb = kstep * 32 + (lane >> 4) * 8;
#pragma unroll
            for (int t = 0; t < 8; t++) tmp[t] = f2bf(W1[f * 64 + kb + t]);
            *(bf16x8_t*)&W1P[(size_t)u * 8] = *(bf16x8_t*)tmp;
        } else if (tid < 34688) {   // W2 (K=32, upper half zero)
            int u = tid - 34432, lane = u & 63, nt = u >> 6;
            int o = nt * 16 + (lane & 15), kb = (lane >> 4) * 8;
#pragma unroll
            for (int t = 0; t < 8; t++) { int k = kb + t; tmp[t] = (k < 16) ? f2bf(W2[o * 16 + k]) : (short)0; }
            *(bf16x8_t*)&W2P[(size_t)u * 8] = *(bf16x8_t*)tmp;
        } else if (tid < 34816) {   // Wc (cols >=4 zero)
            int u = tid - 34688, lane = u & 63, kstep = u >> 6;
            int m = lane & 15, kb = kstep * 32 + (lane >> 4) * 8;
#pragma unroll
            for (int t = 0; t < 8; t++) tmp[t] = (m < 4) ? f2bf(Wc[m * 64 + kb + t]) : (short)0;
            *(bf16x8_t*)&WcP[(size_t)u * 8] = *(bf16x8_t*)tmp;
        }
    } else if (bx == 136) {
        if (threadIdx.x < 64) {
            int lane = threadIdx.x;
            float ksep = bqkv[64 + lane], vsep = bqkv[128 + lane];
            for (int c = 0; c < 64; c++) {
                float sc = SEP[c];
                ksep += Wqkv[(64 + lane) * 64 + c] * sc;
                vsep += Wqkv[(128 + lane) * 64 + c] * sc;
            }
            consts[C_VSEP + lane] = vsep;
            for (int i = 0; i < 4; i++) {
                float q0 = bqkv[lane], kcls = bqkv[64 + lane], vcls = bqkv[128 + lane];
                for (int c = 0; c < 64; c++) {
                    float cc = CLS[i * 64 + c];
                    q0   += Wqkv[lane * 64 + c] * cc;
                    kcls += Wqkv[(64 + lane) * 64 + c] * cc;
                    vcls += Wqkv[(128 + lane) * 64 + c] * cc;
                }
                consts[C_Q0 + i * 64 + lane] = q0;
                consts[C_VCLS + i * 64 + lane] = vcls;
                float p00 = head_sum16(q0 * kcls) * 0.25f;
                float p02 = head_sum16(q0 * ksep) * 0.25f;
                if ((lane & 15) == 0) {
                    consts[C_S00 + i * 4 + (lane >> 4)] = p00;
                    consts[C_S02 + i * 4 + (lane >> 4)] = p02;
                }
            }
        }
    } else {
        __shared__ int h[8];
        int chunk = bx - 137;
        int tid = threadIdx.x;
        if (tid < 8) h[tid] = 0;
        __syncthreads();
        int e = chunk * 256 + tid;
        if (e < E) {
            atomicAdd(&h[etype[e]], 1);
            atomicAdd(&cnt[dst[e]], 1);
        }
        __syncthreads();
        if (tid < 8) hist[chunk * 8 + tid] = h[tid];
    }
}

// ---------------- scan (1 block, 64 lanes) + pack score-projection Wqk
__global__ void k_scan(const int* __restrict__ hist, int* __restrict__ chunkoff,
                       int* __restrict__ startg, int* __restrict__ countsg, int nch,
                       const float* __restrict__ consts, const float* __restrict__ Wqkv,
                       const float* __restrict__ bqkv,
                       short* __restrict__ WqkP, float* __restrict__ bqk)
{
    int lane = threadIdx.x;          // 64: lane = seg*8 + g
    int g = lane & 7, seg = lane >> 3;
    int per = (nch + 7) / 8;
    int c0 = seg * per, c1 = c0 + per; if (c1 > nch) c1 = nch;
    int sum = 0;
    for (int c = c0; c < c1; c++) sum += hist[c * 8 + g];
    int pre = 0, tot = 0;
#pragma unroll
    for (int s2 = 0; s2 < 8; s2++) {
        int v = __shfl(sum, s2 * 8 + g, 64);
        tot += v;
        if (s2 < seg) pre += v;
    }
    int run = pre;
    for (int c = c0; c < c1; c++) { chunkoff[c * 8 + g] = run; run += hist[c * 8 + g]; }
    if (seg == 0) {
        countsg[g] = tot;
        int sg = 0;
#pragma unroll
        for (int g2 = 0; g2 < 8; g2++) { int v = __shfl(tot, g2, 64); if (g2 < g) sg += v; }
        startg[g] = sg;
    }

    // ---- Wqk pack: frag P[(kstep*64+lane)*8+t] = Wqk[lane&15][kstep*32+(lane>>4)*8+t]
    int ih = lane & 15, ii = ih & 3, hh = ih >> 2;
    int lh8 = (lane >> 4) * 8;
    short tmp[8];
#pragma unroll
    for (int kstep = 0; kstep < 2; kstep++) {
#pragma unroll
        for (int t = 0; t < 8; t++) {
            int k = kstep * 32 + lh8 + t;
            float s = 0.f;
            for (int u = 0; u < 16; u++)
                s += consts[C_Q0 + ii * 64 + hh * 16 + u] * Wqkv[(64 + hh * 16 + u) * 64 + k];
            tmp[t] = f2bf(0.25f * s);
        }
        *(bf16x8_t*)&WqkP[(size_t)(kstep * 64 + lane) * 8] = *(bf16x8_t*)tmp;
    }
    if (lane < 16) {
        float s = 0.f;
        for (int u = 0; u < 16; u++)
            s += consts[C_Q0 + ii * 64 + hh * 16 + u] * bqkv[64 + hh * 16 + u];
        bqk[lane] = 0.25f * s;
    }
}

// ---------------- v-projection + per-node attention scores qs via MFMA: 64 nodes/block
__global__ __launch_bounds__(256) void k_kv(const float* __restrict__ feat,
        const short* __restrict__ WkvP, const short* __restrict__ WqkP,
        const float* __restrict__ bqkv, const float* __restrict__ bqk,
        float* __restrict__ vnode, float* __restrict__ qs, int N)
{
    __shared__ __align__(16) short sA[64 * 72];
    int tid = threadIdx.x, lane = tid & 63, w = tid >> 6;
    int l15 = lane & 15, lh = lane >> 4;
    int base = blockIdx.x * 64;
#pragma unroll
    for (int rr = 0; rr < 16; rr++) {
        int row = w * 16 + rr;
        int n = base + row; n = n < N ? n : N - 1;
        sA[row * 72 + lane] = f2bf(feat[(size_t)n * 64 + lane]);
    }
    __syncthreads();
    const bf16x8_t* bp = (const bf16x8_t*)WkvP;
    bf16x8_t bv0 = bp[(0 * 8 + 4 + w) * 64 + lane];
    bf16x8_t bv1 = bp[(1 * 8 + 4 + w) * 64 + lane];
    bf16x8_t bq0 = ((const bf16x8_t*)WqkP)[lane];
    bf16x8_t bq1 = ((const bf16x8_t*)WqkP)[64 + lane];
    int kof = lh * 8;
    int col = w * 16 + l15;
    float biasv = bqkv[128 + col];
    float bqv = bqk[l15];
#pragma unroll
    for (int rt = 0; rt < 4; rt++) {
        bf16x8_t a0 = *(const bf16x8_t*)&sA[(rt * 16 + l15) * 72 + kof];
        bf16x8_t a1 = *(const bf16x8_t*)&sA[(rt * 16 + l15) * 72 + 32 + kof];
        f32x4_t av = {0.f, 0.f, 0.f, 0.f};
        av = MFMA(a0, bv0, av); av = MFMA(a1, bv1, av);
#pragma unroll
        for (int r = 0; r < 4; r++) {
            int n = base + rt * 16 + lh * 4 + r;
            if (n < N) vnode[(size_t)n * 64 + col] = av[r] + biasv;
        }
        if (w == 0) {
            f32x4_t aq = {0.f, 0.f, 0.f, 0.f};
            aq = MFMA(a0, bq0, aq); aq = MFMA(a1, bq1, aq);
#pragma unroll
            for (int r = 0; r < 4; r++) {
                int n = base + rt * 16 + lh * 4 + r;
                if (n < N) qs[(size_t)n * 16 + l15] = aq[r] + bqv;
            }
        }
    }
}

struct EncW {
    const float* consts; const float* CLS; const float* bo;
    const float* b1; const float* b2;
    const float* ln1w; const float* ln1b; const float* ln2w; const float* ln2b;
    const short* WoP; const short* W1P; const short* W2P; const short* WcP;
    const float* bc;
};

// ---------------- batched encoder: 16 units x 4 CLS = 64 rows per block.
// Softmax without max-shift (scores tiny; shift-invariant): per-i constants
// attc = e0*vcls + e2*vsep, esum0 = e0+e2 hoisted out of the unit loop.
__global__ __launch_bounds__(256) void k_enc(const int* __restrict__ src_idx,
        const int* __restrict__ dst_idx,
        const float* __restrict__ vnode, const float* __restrict__ qs, EncW W,
        float* __restrict__ mem_out, float* __restrict__ cat_out, int E, int M)
{
    __shared__ __align__(16) short sA[64 * 72];   // att -> y -> t (wave-private rows)
    __shared__ __align__(16) short sF[64 * 40];   // ff, k=16..31 zero-padded
    int tid = threadIdx.x, lane = tid & 63, w = tid >> 6;
    int l15 = lane & 15, lh = lane >> 4;
    int base = blockIdx.x * 16;

#pragma unroll
    for (int z = 0; z < 4; z++) {
        int zz = z * 64 + lane;
        sF[(w * 16 + (zz >> 4)) * 40 + 16 + (zz & 15)] = 0;
    }

    float attc[4], esum0[4];
#pragma unroll
    for (int i = 0; i < 4; i++) {
        float e0 = __expf(W.consts[C_S00 + i * 4 + lh]);
        float e2 = __expf(W.consts[C_S02 + i * 4 + lh]);
        attc[i]  = e0 * W.consts[C_VCLS + i * 64 + lane] + e2 * W.consts[C_VSEP + lane];
        esum0[i] = e0 + e2;
    }

    // ---- attention phase: scores from qs, v gathers only, no max-shift
#pragma unroll
    for (int el = 0; el < 4; el++) {
        int eloc = w * 4 + el;
        int ge = base + eloc; int gc = ge < M ? ge : M - 1;
        int s, d;
        if (gc < E) { s = src_idx[gc]; d = dst_idx[gc]; }
        else        { s = gc - E; d = s; }
        float vs_ = vnode[(size_t)s * 64 + lane];
        float vd  = vnode[(size_t)d * 64 + lane];
        float4 qh_s = *(const float4*)&qs[(size_t)s * 16 + lh * 4];
        float4 qh_d = *(const float4*)&qs[(size_t)d * 16 + lh * 4];
        float qsv[4] = {qh_s.x, qh_s.y, qh_s.z, qh_s.w};
        float qdv[4] = {qh_d.x, qh_d.y, qh_d.z, qh_d.w};
#pragma unroll
        for (int i = 0; i < 4; i++) {
            float e1 = __expf(qsv[i]), e3 = __expf(qdv[i]);
            float inv = 1.0f / (esum0[i] + e1 + e3);
            float att = (attc[i] + e1 * vs_ + e3 * vd) * inv;
            sA[(eloc * 4 + i) * 72 + lane] = f2bf(att);
        }
    }

    int arow = (w * 16 + l15) * 72;
    int kof = lh * 8;

    const bf16x8_t* bpo = (const bf16x8_t*)W.WoP;
    f32x4_t ac0 = {0.f,0.f,0.f,0.f}, ac1 = ac0, ac2 = ac0, ac3 = ac0;
#pragma unroll
    for (int kstep = 0; kstep < 2; kstep++) {
        bf16x8_t a = *(const bf16x8_t*)&sA[arow + kstep * 32 + kof];
        ac0 = MFMA(a, bpo[(kstep * 4 + 0) * 64 + lane], ac0);
        ac1 = MFMA(a, bpo[(kstep * 4 + 1) * 64 + lane], ac1);
        ac2 = MFMA(a, bpo[(kstep * 4 + 2) * 64 + lane], ac2);
        ac3 = MFMA(a, bpo[(kstep * 4 + 3) * 64 + lane], ac3);
    }

    float x[4][4], y[4][4];
#pragma unroll
    for (int r = 0; r < 4; r++) { x[0][r] = ac0[r]; x[1][r] = ac1[r]; x[2][r] = ac2[r]; x[3][r] = ac3[r]; }
    float lw1[4], lb1[4];
#pragma unroll
    for (int nt = 0; nt < 4; nt++) {
        float b = W.bo[nt * 16 + l15];
        lw1[nt] = W.ln1w[nt * 16 + l15]; lb1[nt] = W.ln1b[nt * 16 + l15];
#pragma unroll
        for (int r = 0; r < 4; r++) x[nt][r] += b + W.CLS[r * 64 + nt * 16 + l15];
    }
#pragma unroll
    for (int r = 0; r < 4; r++) {
        float sm = head_sum16(x[0][r] + x[1][r] + x[2][r] + x[3][r]);
        float mu = sm * 0.015625f;
        float vv = 0.f;
#pragma unroll
        for (int nt = 0; nt < 4; nt++) { float dd = x[nt][r] - mu; vv = fmaf(dd, dd, vv); }
        vv = head_sum16(vv);
        float rs = rsqrtf(vv * 0.015625f + 1e-5f);
#pragma unroll
        for (int nt = 0; nt < 4; nt++) y[nt][r] = (x[nt][r] - mu) * rs * lw1[nt] + lb1[nt];
    }
#pragma unroll
    for (int nt = 0; nt < 4; nt++)
#pragma unroll
        for (int r = 0; r < 4; r++)
            sA[(w * 16 + lh * 4 + r) * 72 + nt * 16 + l15] = f2bf(y[nt][r]);

    const bf16x8_t* bp1 = (const bf16x8_t*)W.W1P;
    f32x4_t fa = {0.f,0.f,0.f,0.f};
#pragma unroll
    for (int kstep = 0; kstep < 2; kstep++) {
        bf16x8_t a = *(const bf16x8_t*)&sA[arow + kstep * 32 + kof];
        fa = MFMA(a, bp1[kstep * 64 + lane], fa);
    }
    float b1v = W.b1[l15];
#pragma unroll
    for (int r = 0; r < 4; r++)
        sF[(w * 16 + lh * 4 + r) * 40 + l15] = f2bf(fmaxf(fa[r] + b1v, 0.f));

    const bf16x8_t* bp2 = (const bf16x8_t*)W.W2P;
    bf16x8_t af = *(const bf16x8_t*)&sF[(w * 16 + l15) * 40 + kof];
    f32x4_t z0 = {0.f,0.f,0.f,0.f}, z1 = z0, z2 = z0, z3 = z0;
    z0 = MFMA(af, bp2[0 * 64 + lane], z0);
    z1 = MFMA(af, bp2[1 * 64 + lane], z1);
    z2 = MFMA(af, bp2[2 * 64 + lane], z2);
    z3 = MFMA(af, bp2[3 * 64 + lane], z3);

    float t[4][4];
#pragma unroll
    for (int r = 0; r < 4; r++) { x[0][r] = z0[r]; x[1][r] = z1[r]; x[2][r] = z2[r]; x[3][r] = z3[r]; }
    float lw2[4], lb2[4];
#pragma unroll
    for (int nt = 0; nt < 4; nt++) {
        float b = W.b2[nt * 16 + l15];
        lw2[nt] = W.ln2w[nt * 16 + l15]; lb2[nt] = W.ln2b[nt * 16 + l15];
#pragma unroll
        for (int r = 0; r < 4; r++) x[nt][r] += b + y[nt][r];
    }
#pragma unroll
    for (int r = 0; r < 4; r++) {
        float sm = head_sum16(x[0][r] + x[1][r] + x[2][r] + x[3][r]);
        float mu = sm * 0.015625f;
        float vv = 0.f;
#pragma unroll
        for (int nt = 0; nt < 4; nt++) { float dd = x[nt][r] - mu; vv = fmaf(dd, dd, vv); }
        vv = head_sum16(vv);
        float rs = rsqrtf(vv * 0.015625f + 1e-5f);
#pragma unroll
        for (int nt = 0; nt < 4; nt++) t[nt][r] = (x[nt][r] - mu) * rs * lw2[nt] + lb2[nt];
    }

    int eloc = w * 4 + lh, ge = base + eloc;

    if (base < E) {
#pragma unroll
        for (int nt = 0; nt < 4; nt++)
#pragma unroll
            for (int r = 0; r < 4; r++)
                sA[(w * 16 + lh * 4 + r) * 72 + nt * 16 + l15] = f2bf(t[nt][r]);
        const bf16x8_t* bpc = (const bf16x8_t*)W.WcP;
        f32x4_t ca = {0.f,0.f,0.f,0.f};
#pragma unroll
        for (int kstep = 0; kstep < 2; kstep++) {
            bf16x8_t a = *(const bf16x8_t*)&sA[arow + kstep * 32 + kof];
            ca = MFMA(a, bpc[kstep * 64 + lane], ca);
        }
        if (l15 < 4 && ge < E) {
            float bcv = W.bc[l15];
#pragma unroll
            for (int r = 0; r < 4; r++)
                cat_out[((size_t)r * E + ge) * 4 + l15] = ca[r] + bcv;
        }
    }

    if (ge < M) {
#pragma unroll
        for (int nt = 0; nt < 4; nt++)
            mem_out[(size_t)ge * 64 + nt * 16 + l15] = t[nt][0] + t[nt][1] + t[nt][2] + t[nt][3];
    }
}

// ---------------- hypernetwork bilinear v7 "P-scheme" (reverted, known 63us):
// 128 rows/block, 2-i chunks, double-buffered, counted vmcnt.
__global__ __launch_bounds__(256, 3) void k_hyper(
        const float* __restrict__ feat, const int* __restrict__ src_idx,
        const int* __restrict__ dst_idx, const float* __restrict__ memall,
        const short* __restrict__ Bpack,
        float* __restrict__ agg, float* __restrict__ selfm, int E, int M)
{
    __shared__ short xsT[64 * 132];                 // bf16 x^T: [i][row]
    __shared__ __align__(16) short sB[2][8192];     // 2 x 16KB: 2-i B-frag chunks
    int tid = threadIdx.x, lane = tid & 63, w = tid >> 6;
    int l15 = lane & 15, lh = lane >> 4, koff = lh * 8;
    int base = blockIdx.x * 128;

    const bf16x8_t* bp = (const bf16x8_t*)Bpack;

    auto stage = [&](int c, int buf) {
#pragma unroll
        for (int jj = 0; jj < 4; ++jj) {
            int j = w * 4 + jj;
            int il_ic = j >> 3, q = j & 7;
            const short* src = (const short*)(bp + (size_t)(c * 2 + il_ic) * 512
                                              + (q >> 2) * 256 + (q & 3) * 64 + lane);
            short* dst = &sB[buf][j * 512];
            __builtin_amdgcn_global_load_lds(
                (const __attribute__((address_space(1))) void*)src,
                (__attribute__((address_space(3))) void*)dst, 16, 0, 0);
        }
    };

    stage(0, 0);

    for (int rr = 0; rr < 32; ++rr) {
        int row = w * 32 + rr, gr = base + row;
        float xv = 0.f;
        if (gr < M) {
            int xi = gr < E ? src_idx[gr] : gr - E;
            xv = feat[(size_t)xi * 64 + lane];
        }
        xsT[lane * 132 + row] = f2bf(xv);
    }

    bf16x8_t am[2][2];
#pragma unroll
    for (int tt = 0; tt < 2; ++tt) {
        int gr = base + w * 32 + tt * 16 + l15;
        const float* mp = memall + (size_t)(gr < M ? gr : 0) * 64 + koff;
#pragma unroll
        for (int kk = 0; kk < 2; ++kk)
#pragma unroll
            for (int t = 0; t < 8; ++t)
                am[tt][kk][t] = f2bf(mp[kk * 32 + t]);
    }

    f32x4_t out[2][4];
#pragma unroll
    for (int tt = 0; tt < 2; ++tt)
#pragma unroll
        for (int nt = 0; nt < 4; ++nt) out[tt][nt] = (f32x4_t){0.f, 0.f, 0.f, 0.f};
    const f32x4_t ZERO = {0.f, 0.f, 0.f, 0.f};

    int xrow0 = w * 32 + lh * 4;

    int cur = 0;
    for (int c = 0; c < 32; ++c) {
        if (c + 1 < 32) {
            stage(c + 1, cur ^ 1);
            asm volatile("s_waitcnt vmcnt(4)" ::: "memory");
        } else {
            asm volatile("s_waitcnt vmcnt(0)" ::: "memory");
        }
        __builtin_amdgcn_s_barrier();
#pragma unroll
        for (int ic = 0; ic < 2; ++ic) {
            int i = c * 2 + ic;
            unsigned long long xw0 = *(const unsigned long long*)&xsT[i * 132 + xrow0];
            unsigned long long xw1 = *(const unsigned long long*)&xsT[i * 132 + xrow0 + 16];
            float x0[4], x1[4];
            {
                unsigned lo0 = (unsigned)xw0, hi0 = (unsigned)(xw0 >> 32);
                unsigned lo1 = (unsigned)xw1, hi1 = (unsigned)(xw1 >> 32);
                x0[0] = __builtin_bit_cast(float, lo0 << 16);
                x0[1] = __builtin_bit_cast(float, lo0 & 0xffff0000u);
                x0[2] = __builtin_bit_cast(float, hi0 << 16);
                x0[3] = __builtin_bit_cast(float, hi0 & 0xffff0000u);
                x1[0] = __builtin_bit_cast(float, lo1 << 16);
                x1[1] = __builtin_bit_cast(float, lo1 & 0xffff0000u);
                x1[2] = __builtin_bit_cast(float, hi1 << 16);
                x1[3] = __builtin_bit_cast(float, hi1 & 0xffff0000u);
            }
            const bf16x8_t* bfr = (const bf16x8_t*)&sB[cur][ic * 4096];
            f32x4_t P0[4], P1[4];
            __builtin_amdgcn_s_setprio(1);
#pragma unroll
            for (int nt = 0; nt < 4; ++nt) {
                bf16x8_t B0 = bfr[nt * 64 + lane];
                bf16x8_t B1 = bfr[(4 + nt) * 64 + lane];
                P0[nt] = MFMA(am[0][0], B0, ZERO);
                P1[nt] = MFMA(am[1][0], B0, ZERO);
                P0[nt] = MFMA(am[0][1], B1, P0[nt]);
                P1[nt] = MFMA(am[1][1], B1, P1[nt]);
            }
            __builtin_amdgcn_s_setprio(0);
#pragma unroll
            for (int nt = 0; nt < 4; ++nt)
#pragma unroll
                for (int r = 0; r < 4; ++r) {
                    out[0][nt][r] = fmaf(x0[r], P0[nt][r], out[0][nt][r]);
                    out[1][nt][r] = fmaf(x1[r], P1[nt][r], out[1][nt][r]);
                }
        }
        __builtin_amdgcn_s_barrier();
        cur ^= 1;
    }

#pragma unroll
    for (int tt = 0; tt < 2; ++tt) {
        int orow = w * 32 + tt * 16 + lh * 4;
        int di[4];
#pragma unroll
        for (int r = 0; r < 4; ++r) {
            int grow = base + orow + r;
            di[r] = (grow < E) ? dst_idx[grow] : 0;
        }
#pragma unroll
        for (int nt = 0; nt < 4; ++nt) {
            int o = nt * 16 + l15;
#pragma unroll
            for (int r = 0; r < 4; ++r) {
                int grow = base + orow + r;
                if (grow < M) {
                    float v = out[tt][nt][r];
                    if (grow < E) atomicAdd(&agg[(size_t)di[r] * 64 + o], v);
                    else selfm[(size_t)(grow - E) * 64 + o] = v;
                }
            }
        }
    }
}

// ---------------- finalize + scatter merged: blocks [0,FB) fin, [FB,FB+NCH) scatter
__global__ __launch_bounds__(256) void k_finsc(
        const float* __restrict__ agg, const int* __restrict__ cnt,
        const float* __restrict__ selfm, const float* __restrict__ h_bias,
        float* __restrict__ outp, int N,
        const int* __restrict__ etype, const float* __restrict__ cat_all,
        const int* __restrict__ chunkoff, const int* __restrict__ startg,
        const int* __restrict__ countsg,
        float* __restrict__ out_label, float* __restrict__ out_cat, int E, int FB)
{
    if ((int)blockIdx.x < FB) {
        int t = blockIdx.x * 256 + threadIdx.x;
        if (t < N * 64) {
            int n = t >> 6, o = t & 63;
            int c = cnt[n];
            float av = (c > 0) ? agg[t] / (float)c : 0.f;
            outp[t] = av + h_bias[o] + selfm[t];
        }
    } else {
        __shared__ int wc[4][8];
        int tid = threadIdx.x, lane = tid & 63, w = tid >> 6;
        int chunk = blockIdx.x - FB;
        int e = chunk * 256 + w * 64 + lane;
        int et = (e < E) ? etype[e] : -1;
        unsigned long long mk[8];
#pragma unroll
        for (int g = 0; g < 8; g++) mk[g] = __ballot(et == g);
        if (lane < 8) wc[w][lane] = (int)__popcll(mk[lane]);
        __syncthreads();
        if (et >= 0) {
            unsigned long long lt = (1ull << lane) - 1ull;
            int myr = chunkoff[chunk * 8 + et] + (int)__popcll(mk[et] & lt);
#pragma unroll
            for (int w2 = 0; w2 < 4; w2++) if (w2 < w) myr += wc[w2][et];
            int sg = startg[et], cg = countsg[et];
            size_t pbase = (size_t)sg * 4 + myr;
#pragma unroll
            for (int i = 0; i < 4; i++) {
                size_t pos = pbase + (size_t)i * cg;
                out_label[pos] = (float)i;
                const float* ca = &cat_all[((size_t)i * E + e) * 4];
                float4 cv = {ca[0], ca[1], ca[2], ca[3]};
                *(float4*)&out_cat[pos * 4] = cv;
            }
        }
    }
}

extern "C" void kernel_launch(void* const* d_in, const int* in_sizes, int n_in,
                              void* d_out, int out_size, void* d_ws, size_t ws_size,
                              hipStream_t stream)
{
    const float* feat    = (const float*)d_in[0];
    const int*   src_idx = (const int*)d_in[1];
    const int*   dst_idx = (const int*)d_in[2];
    const int*   etype   = (const int*)d_in[3];
    const float* Wqkv    = (const float*)d_in[4];
    const float* bqkv    = (const float*)d_in[5];
    const float* Wo      = (const float*)d_in[6];
    const float* bo      = (const float*)d_in[7];
    const float* W1      = (const float*)d_in[8];
    const float* b1      = (const float*)d_in[9];
    const float* W2      = (const float*)d_in[10];
    const float* b2      = (const float*)d_in[11];
    const float* ln1w    = (const float*)d_in[12];
    const float* ln1b    = (const float*)d_in[13];
    const float* ln2w    = (const float*)d_in[14];
    const float* ln2b    = (const float*)d_in[15];
    const float* Wc      = (const float*)d_in[16];
    const float* bc      = (const float*)d_in[17];
    const float* CLS     = (const float*)d_in[18];
    const float* SEP     = (const float*)d_in[19];
    const float* Wm      = (const float*)d_in[20];
    const float* h_bias  = (const float*)d_in[21];

    const int N = in_sizes[0] / 64;
    const int E = in_sizes[1];
    const int M = E + N;                 // total hyper/encoder units
    const int NCH = (E + 255) / 256;
    const int FB = (N * 64 + 255) / 256;

    float* ws = (float*)d_ws;
    size_t off = 0;
    auto alloc = [&](size_t n) { float* p = ws + off; off += (n + 63) & ~(size_t)63; return p; };
    float* qs      = alloc((size_t)N * 16);          // per-node attention scores [N][h*4+i]
    float* vnode   = alloc((size_t)N * 64);
    float* mem_all = alloc((size_t)M * 64);          // [0,E) edge, [E,M) self
    float* cat_all = alloc((size_t)E * 16);
    float* agg     = alloc((size_t)N * 64 + N);      // agg + cnt contiguous for one memset
    int*   cnt     = (int*)(agg + (size_t)N * 64);
    float* selfm   = alloc((size_t)N * 64);
    float* consts  = alloc(1024);
    short* Bpack   = (short*)alloc(131072);          // 262144 bf16
    short* WoP     = (short*)alloc(2048);
    short* WkvP    = (short*)alloc(4096);
    short* W1P     = (short*)alloc(512);
    short* W2P     = (short*)alloc(1024);
    short* WcP     = (short*)alloc(512);
    short* WqkP    = (short*)alloc(512);             // 1024 bf16
    float* bqk     = alloc(64);
    int*   hist    = (int*)alloc(NCH * 8);
    int*   chunkoff= (int*)alloc(NCH * 8);
    int*   startg  = (int*)alloc(8);
    int*   countsg = (int*)alloc(8);

    float* out_node  = (float*)d_out;
    float* out_label = out_node + (size_t)N * 64;
    float* out_cat   = out_label + (size_t)4 * E;

    hipMemsetAsync(agg, 0, ((size_t)N * 64 + N) * sizeof(float), stream);

    k_prep<<<137 + NCH, 256, 0, stream>>>(Wo, Wqkv, W1, W2, Wm, Wc, bqkv, CLS, SEP,
                                          etype, dst_idx, Bpack, WoP, WkvP, W1P, W2P, WcP,
                                          consts, hist, cnt, E);
    k_scan<<<1, 64, 0, stream>>>(hist, chunkoff, startg, countsg, NCH,
                                 consts, Wqkv, bqkv, WqkP, bqk);

    k_kv<<<(N + 63) / 64, 256, 0, stream>>>(feat, WkvP, WqkP, bqkv, bqk, vnode, qs, N);

    EncW W{consts, CLS, bo, b1, b2, ln1w, ln1b, ln2w, ln2b, WoP, W1P, W2P, WcP, bc};

    k_enc<<<(M + 15) / 16, 256, 0, stream>>>(src_idx, dst_idx, vnode, qs, W,
                                             mem_all, cat_all, E, M);

    k_hyper<<<(M + 127) / 128, 256, 0, stream>>>(feat, src_idx, dst_idx, mem_all, Bpack,
                                                 agg, selfm, E, M);

    k_finsc<<<FB + NCH, 256, 0, stream>>>(agg, cnt, selfm, h_bias, out_node, N,
                                          etype, cat_all, chunkoff, startg, countsg,
                                          out_label, out_cat, E, FB);
}

// Round 12
// 137.724 us; speedup vs baseline: 1.1773x; 1.0691x over previous
//
#include <hip/hip_runtime.h>
#include <hip/hip_bf16.h>

typedef float f32x4_t __attribute__((ext_vector_type(4)));
typedef short bf16x8_t __attribute__((ext_vector_type(8)));

#define MFMA(a, b, c) __builtin_amdgcn_mfma_f32_16x16x32_bf16(a, b, c, 0, 0, 0)

// consts layout offsets (floats)
#define C_Q0   0      // [4][64] q of token0 per CLS
#define C_S00  256    // [4][4]  score(q0,k_cls)/4 per head
#define C_S02  272    // [4][4]  score(q0,k_sep)/4 per head
#define C_VCLS 288    // [4][64]
#define C_VSEP 544    // [64]

__device__ __forceinline__ short f2bf(float x) {
    return (short)__builtin_bit_cast(unsigned short, __float2bfloat16(x));
}
__device__ __forceinline__ float bf2f(short s) {
    return __builtin_bit_cast(float, ((unsigned)(unsigned short)s) << 16);
}
__device__ __forceinline__ float head_sum16(float v) {
#pragma unroll
    for (int off = 1; off < 16; off <<= 1) v += __shfl_xor(v, off, 64);
    return v;
}

// ---------------- combo prep kernel: pack + consts + Wqk-pack + hist/cnt
// blocks [0,136): pack; 136: consts; 137: Wqk pack; [138,138+NCH): hist+cnt.
__global__ void k_prep(const float* __restrict__ Wo, const float* __restrict__ Wqkv,
                       const float* __restrict__ W1, const float* __restrict__ W2,
                       const float* __restrict__ Wm, const float* __restrict__ Wc,
                       const float* __restrict__ bqkv,
                       const float* __restrict__ CLS, const float* __restrict__ SEP,
                       const int* __restrict__ etype, const int* __restrict__ dst,
                       short* __restrict__ Bpack, short* __restrict__ WoP,
                       short* __restrict__ WkvP, short* __restrict__ W1P,
                       short* __restrict__ W2P, short* __restrict__ WcP,
                       float* __restrict__ consts,
                       short* __restrict__ WqkP, float* __restrict__ bqk,
                       int* __restrict__ hist, int* __restrict__ cnt, int E)
{
    int bx = blockIdx.x;
    if (bx < 136) {
        int tid = bx * 256 + threadIdx.x;
        short tmp[8];
        if (tid < 32768) {          // Wm: B[k=i*64+j][o] = Wm[(o*64+i)*64+j]
            int u = tid, lane = u & 63, nt = (u >> 6) & 3, kstep = u >> 8;
            int o = nt * 16 + (lane & 15);
            int kb = kstep * 32 + (lane >> 4) * 8;
#pragma unroll
            for (int t = 0; t < 8; t++) { int k = kb + t; tmp[t] = f2bf(Wm[(o * 64 + (k >> 6)) * 64 + (k & 63)]); }
            *(bf16x8_t*)&Bpack[(size_t)u * 8] = *(bf16x8_t*)tmp;
        } else if (tid < 33280) {   // Wo: B[k=c][o] = Wo[o*64+c]
            int u = tid - 32768, lane = u & 63, nt = (u >> 6) & 3, kstep = u >> 8;
            int o = nt * 16 + (lane & 15), kb = kstep * 32 + (lane >> 4) * 8;
#pragma unroll
            for (int t = 0; t < 8; t++) tmp[t] = f2bf(Wo[o * 64 + kb + t]);
            *(bf16x8_t*)&WoP[(size_t)u * 8] = *(bf16x8_t*)tmp;
        } else if (tid < 34304) {   // Wk|Wv
            int u = tid - 33280, lane = u & 63, nt = (u >> 6) & 7, kstep = u >> 9;
            int col = nt * 16 + (lane & 15), kb = kstep * 32 + (lane >> 4) * 8;
            int row = 64 + col;
#pragma unroll
            for (int t = 0; t < 8; t++) tmp[t] = f2bf(Wqkv[row * 64 + kb + t]);
            *(bf16x8_t*)&WkvP[(size_t)u * 8] = *(bf16x8_t*)tmp;
        } else if (tid < 34432) {   // W1
            int u = tid - 34304, lane = u & 63, kstep = u >> 6;
            int f = lane & 15, kb = kstep * 32 + (lane >> 4) * 8;
#pragma unroll
            for (int t = 0; t < 8; t++) tmp[t] = f2bf(W1[f * 64 + kb + t]);
            *(bf16x8_t*)&W1P[(size_t)u * 8] = *(bf16x8_t*)tmp;
        } else if (tid < 34688) {   // W2 (K=32, upper half zero)
            int u = tid - 34432, lane = u & 63, nt = u >> 6;
            int o = nt * 16 + (lane & 15), kb = (lane >> 4) * 8;
#pragma unroll
            for (int t = 0; t < 8; t++) { int k = kb + t; tmp[t] = (k < 16) ? f2bf(W2[o * 16 + k]) : (short)0; }
            *(bf16x8_t*)&W2P[(size_t)u * 8] = *(bf16x8_t*)tmp;
        } else if (tid < 34816) {   // Wc (cols >=4 zero)
            int u = tid - 34688, lane = u & 63, kstep = u >> 6;
            int m = lane & 15, kb = kstep * 32 + (lane >> 4) * 8;
#pragma unroll
            for (int t = 0; t < 8; t++) tmp[t] = (m < 4) ? f2bf(Wc[m * 64 + kb + t]) : (short)0;
            *(bf16x8_t*)&WcP[(size_t)u * 8] = *(bf16x8_t*)tmp;
        }
    } else if (bx == 136) {
        if (threadIdx.x < 64) {
            int lane = threadIdx.x;
            float ksep = bqkv[64 + lane], vsep = bqkv[128 + lane];
            for (int c = 0; c < 64; c++) {
                float sc = SEP[c];
                ksep += Wqkv[(64 + lane) * 64 + c] * sc;
                vsep += Wqkv[(128 + lane) * 64 + c] * sc;
            }
            consts[C_VSEP + lane] = vsep;
            for (int i = 0; i < 4; i++) {
                float q0 = bqkv[lane], kcls = bqkv[64 + lane], vcls = bqkv[128 + lane];
                for (int c = 0; c < 64; c++) {
                    float cc = CLS[i * 64 + c];
                    q0   += Wqkv[lane * 64 + c] * cc;
                    kcls += Wqkv[(64 + lane) * 64 + c] * cc;
                    vcls += Wqkv[(128 + lane) * 64 + c] * cc;
                }
                consts[C_Q0 + i * 64 + lane] = q0;
                consts[C_VCLS + i * 64 + lane] = vcls;
                float p00 = head_sum16(q0 * kcls) * 0.25f;
                float p02 = head_sum16(q0 * ksep) * 0.25f;
                if ((lane & 15) == 0) {
                    consts[C_S00 + i * 4 + (lane >> 4)] = p00;
                    consts[C_S02 + i * 4 + (lane >> 4)] = p02;
                }
            }
        }
    } else if (bx == 137) {
        // Wqk pack: wqk[ih=h*4+i][k] = 0.25 * sum_u q0[i][h*16+u]*Wk[h*16+u][k]
        // q0 recomputed locally (1 entry/thread) to avoid cross-block dependency.
        __shared__ float q0s[4][64];
        __shared__ float wqk[16][64];
        int tid = threadIdx.x;
        {
            int i = tid >> 6, c = tid & 63;
            float q0 = bqkv[c];
            for (int c2 = 0; c2 < 64; c2++)
                q0 += Wqkv[c * 64 + c2] * CLS[i * 64 + c2];
            q0s[i][c] = q0;
        }
        __syncthreads();
#pragma unroll
        for (int q = 0; q < 4; q++) {
            int idx = tid * 4 + q;            // 1024 outputs, 4/thread
            int ih = idx >> 6, k = idx & 63;
            int ii = ih & 3, hh = ih >> 2;
            float s = 0.f;
#pragma unroll
            for (int u = 0; u < 16; u++)
                s += q0s[ii][hh * 16 + u] * Wqkv[(64 + hh * 16 + u) * 64 + k];
            wqk[ih][k] = 0.25f * s;
        }
        __syncthreads();
        if (tid < 128) {
            int kstep = tid >> 6, lane = tid & 63;
            short tmp[8];
#pragma unroll
            for (int t = 0; t < 8; t++)
                tmp[t] = f2bf(wqk[lane & 15][kstep * 32 + (lane >> 4) * 8 + t]);
            *(bf16x8_t*)&WqkP[(size_t)(kstep * 64 + lane) * 8] = *(bf16x8_t*)tmp;
        } else if (tid < 144) {
            int ihh = tid - 128, ii = ihh & 3, hh = ihh >> 2;
            float s = 0.f;
#pragma unroll
            for (int u = 0; u < 16; u++)
                s += q0s[ii][hh * 16 + u] * bqkv[64 + hh * 16 + u];
            bqk[ihh] = 0.25f * s;
        }
    } else {
        __shared__ int h[8];
        int chunk = bx - 138;
        int tid = threadIdx.x;
        if (tid < 8) h[tid] = 0;
        __syncthreads();
        int e = chunk * 256 + tid;
        if (e < E) {
            atomicAdd(&h[etype[e]], 1);
            atomicAdd(&cnt[dst[e]], 1);
        }
        __syncthreads();
        if (tid < 8) hist[chunk * 8 + tid] = h[tid];
    }
}

// ---------------- v-proj + score-proj qs via MFMA (64 nodes/block);
// block KB additionally runs the etype-scan (64 lanes).
__global__ __launch_bounds__(256) void k_kv(const float* __restrict__ feat,
        const short* __restrict__ WkvP, const short* __restrict__ WqkP,
        const float* __restrict__ bqkv, const float* __restrict__ bqk,
        float* __restrict__ vnode, float* __restrict__ qs, int N,
        const int* __restrict__ hist, int* __restrict__ chunkoff,
        int* __restrict__ startg, int* __restrict__ countsg, int nch, int KB)
{
    if ((int)blockIdx.x == KB) {
        if (threadIdx.x < 64) {
            int lane = threadIdx.x;          // lane = seg*8 + g
            int g = lane & 7, seg = lane >> 3;
            int per = (nch + 7) / 8;
            int c0 = seg * per, c1 = c0 + per; if (c1 > nch) c1 = nch;
            int sum = 0;
            for (int c = c0; c < c1; c++) sum += hist[c * 8 + g];
            int pre = 0, tot = 0;
#pragma unroll
            for (int s2 = 0; s2 < 8; s2++) {
                int v = __shfl(sum, s2 * 8 + g, 64);
                tot += v;
                if (s2 < seg) pre += v;
            }
            int run = pre;
            for (int c = c0; c < c1; c++) { chunkoff[c * 8 + g] = run; run += hist[c * 8 + g]; }
            if (seg == 0) {
                countsg[g] = tot;
                int sg = 0;
#pragma unroll
                for (int g2 = 0; g2 < 8; g2++) { int v = __shfl(tot, g2, 64); if (g2 < g) sg += v; }
                startg[g] = sg;
            }
        }
        return;
    }
    __shared__ __align__(16) short sA[64 * 72];
    int tid = threadIdx.x, lane = tid & 63, w = tid >> 6;
    int l15 = lane & 15, lh = lane >> 4;
    int base = blockIdx.x * 64;
#pragma unroll
    for (int rr = 0; rr < 16; rr++) {
        int row = w * 16 + rr;
        int n = base + row; n = n < N ? n : N - 1;
        sA[row * 72 + lane] = f2bf(feat[(size_t)n * 64 + lane]);
    }
    __syncthreads();
    const bf16x8_t* bp = (const bf16x8_t*)WkvP;
    bf16x8_t bv0 = bp[(0 * 8 + 4 + w) * 64 + lane];
    bf16x8_t bv1 = bp[(1 * 8 + 4 + w) * 64 + lane];
    bf16x8_t bq0 = ((const bf16x8_t*)WqkP)[lane];
    bf16x8_t bq1 = ((const bf16x8_t*)WqkP)[64 + lane];
    int kof = lh * 8;
    int col = w * 16 + l15;
    float biasv = bqkv[128 + col];
    float bqv = bqk[l15];
#pragma unroll
    for (int rt = 0; rt < 4; rt++) {
        bf16x8_t a0 = *(const bf16x8_t*)&sA[(rt * 16 + l15) * 72 + kof];
        bf16x8_t a1 = *(const bf16x8_t*)&sA[(rt * 16 + l15) * 72 + 32 + kof];
        f32x4_t av = {0.f, 0.f, 0.f, 0.f};
        av = MFMA(a0, bv0, av); av = MFMA(a1, bv1, av);
#pragma unroll
        for (int r = 0; r < 4; r++) {
            int n = base + rt * 16 + lh * 4 + r;
            if (n < N) vnode[(size_t)n * 64 + col] = av[r] + biasv;
        }
        if (w == 0) {
            f32x4_t aq = {0.f, 0.f, 0.f, 0.f};
            aq = MFMA(a0, bq0, aq); aq = MFMA(a1, bq1, aq);
#pragma unroll
            for (int r = 0; r < 4; r++) {
                int n = base + rt * 16 + lh * 4 + r;
                if (n < N) qs[(size_t)n * 16 + l15] = aq[r] + bqv;
            }
        }
    }
}

struct EncW {
    const float* consts; const float* CLS; const float* bo;
    const float* b1; const float* b2;
    const float* ln1w; const float* ln1b; const float* ln2w; const float* ln2b;
    const short* WoP; const short* W1P; const short* W2P; const short* WcP;
    const float* bc;
};

// ---------------- batched encoder: 16 units x 4 CLS = 64 rows per block.
__global__ __launch_bounds__(256) void k_enc(const int* __restrict__ src_idx,
        const int* __restrict__ dst_idx,
        const float* __restrict__ vnode, const float* __restrict__ qs, EncW W,
        float* __restrict__ mem_out, float* __restrict__ cat_out, int E, int M)
{
    __shared__ __align__(16) short sA[64 * 72];   // att -> y -> t (wave-private rows)
    __shared__ __align__(16) short sF[64 * 40];   // ff, k=16..31 zero-padded
    int tid = threadIdx.x, lane = tid & 63, w = tid >> 6;
    int l15 = lane & 15, lh = lane >> 4;
    int base = blockIdx.x * 16;

#pragma unroll
    for (int z = 0; z < 4; z++) {
        int zz = z * 64 + lane;
        sF[(w * 16 + (zz >> 4)) * 40 + 16 + (zz & 15)] = 0;
    }

    float attc[4], esum0[4];
#pragma unroll
    for (int i = 0; i < 4; i++) {
        float e0 = __expf(W.consts[C_S00 + i * 4 + lh]);
        float e2 = __expf(W.consts[C_S02 + i * 4 + lh]);
        attc[i]  = e0 * W.consts[C_VCLS + i * 64 + lane] + e2 * W.consts[C_VSEP + lane];
        esum0[i] = e0 + e2;
    }

    // ---- attention phase: scores from qs, v gathers only, no max-shift
#pragma unroll
    for (int el = 0; el < 4; el++) {
        int eloc = w * 4 + el;
        int ge = base + eloc; int gc = ge < M ? ge : M - 1;
        int s, d;
        if (gc < E) { s = src_idx[gc]; d = dst_idx[gc]; }
        else        { s = gc - E; d = s; }
        float vs_ = vnode[(size_t)s * 64 + lane];
        float vd  = vnode[(size_t)d * 64 + lane];
        float4 qh_s = *(const float4*)&qs[(size_t)s * 16 + lh * 4];
        float4 qh_d = *(const float4*)&qs[(size_t)d * 16 + lh * 4];
        float qsv[4] = {qh_s.x, qh_s.y, qh_s.z, qh_s.w};
        float qdv[4] = {qh_d.x, qh_d.y, qh_d.z, qh_d.w};
#pragma unroll
        for (int i = 0; i < 4; i++) {
            float e1 = __expf(qsv[i]), e3 = __expf(qdv[i]);
            float inv = 1.0f / (esum0[i] + e1 + e3);
            float att = (attc[i] + e1 * vs_ + e3 * vd) * inv;
            sA[(eloc * 4 + i) * 72 + lane] = f2bf(att);
        }
    }

    int arow = (w * 16 + l15) * 72;
    int kof = lh * 8;

    const bf16x8_t* bpo = (const bf16x8_t*)W.WoP;
    f32x4_t ac0 = {0.f,0.f,0.f,0.f}, ac1 = ac0, ac2 = ac0, ac3 = ac0;
#pragma unroll
    for (int kstep = 0; kstep < 2; kstep++) {
        bf16x8_t a = *(const bf16x8_t*)&sA[arow + kstep * 32 + kof];
        ac0 = MFMA(a, bpo[(kstep * 4 + 0) * 64 + lane], ac0);
        ac1 = MFMA(a, bpo[(kstep * 4 + 1) * 64 + lane], ac1);
        ac2 = MFMA(a, bpo[(kstep * 4 + 2) * 64 + lane], ac2);
        ac3 = MFMA(a, bpo[(kstep * 4 + 3) * 64 + lane], ac3);
    }

    float x[4][4], y[4][4];
#pragma unroll
    for (int r = 0; r < 4; r++) { x[0][r] = ac0[r]; x[1][r] = ac1[r]; x[2][r] = ac2[r]; x[3][r] = ac3[r]; }
    float lw1[4], lb1[4];
#pragma unroll
    for (int nt = 0; nt < 4; nt++) {
        float b = W.bo[nt * 16 + l15];
        lw1[nt] = W.ln1w[nt * 16 + l15]; lb1[nt] = W.ln1b[nt * 16 + l15];
#pragma unroll
        for (int r = 0; r < 4; r++) x[nt][r] += b + W.CLS[r * 64 + nt * 16 + l15];
    }
#pragma unroll
    for (int r = 0; r < 4; r++) {
        float sm = head_sum16(x[0][r] + x[1][r] + x[2][r] + x[3][r]);
        float mu = sm * 0.015625f;
        float vv = 0.f;
#pragma unroll
        for (int nt = 0; nt < 4; nt++) { float dd = x[nt][r] - mu; vv = fmaf(dd, dd, vv); }
        vv = head_sum16(vv);
        float rs = rsqrtf(vv * 0.015625f + 1e-5f);
#pragma unroll
        for (int nt = 0; nt < 4; nt++) y[nt][r] = (x[nt][r] - mu) * rs * lw1[nt] + lb1[nt];
    }
#pragma unroll
    for (int nt = 0; nt < 4; nt++)
#pragma unroll
        for (int r = 0; r < 4; r++)
            sA[(w * 16 + lh * 4 + r) * 72 + nt * 16 + l15] = f2bf(y[nt][r]);

    const bf16x8_t* bp1 = (const bf16x8_t*)W.W1P;
    f32x4_t fa = {0.f,0.f,0.f,0.f};
#pragma unroll
    for (int kstep = 0; kstep < 2; kstep++) {
        bf16x8_t a = *(const bf16x8_t*)&sA[arow + kstep * 32 + kof];
        fa = MFMA(a, bp1[kstep * 64 + lane], fa);
    }
    float b1v = W.b1[l15];
#pragma unroll
    for (int r = 0; r < 4; r++)
        sF[(w * 16 + lh * 4 + r) * 40 + l15] = f2bf(fmaxf(fa[r] + b1v, 0.f));

    const bf16x8_t* bp2 = (const bf16x8_t*)W.W2P;
    bf16x8_t af = *(const bf16x8_t*)&sF[(w * 16 + l15) * 40 + kof];
    f32x4_t z0 = {0.f,0.f,0.f,0.f}, z1 = z0, z2 = z0, z3 = z0;
    z0 = MFMA(af, bp2[0 * 64 + lane], z0);
    z1 = MFMA(af, bp2[1 * 64 + lane], z1);
    z2 = MFMA(af, bp2[2 * 64 + lane], z2);
    z3 = MFMA(af, bp2[3 * 64 + lane], z3);

    float t[4][4];
#pragma unroll
    for (int r = 0; r < 4; r++) { x[0][r] = z0[r]; x[1][r] = z1[r]; x[2][r] = z2[r]; x[3][r] = z3[r]; }
    float lw2[4], lb2[4];
#pragma unroll
    for (int nt = 0; nt < 4; nt++) {
        float b = W.b2[nt * 16 + l15];
        lw2[nt] = W.ln2w[nt * 16 + l15]; lb2[nt] = W.ln2b[nt * 16 + l15];
#pragma unroll
        for (int r = 0; r < 4; r++) x[nt][r] += b + y[nt][r];
    }
#pragma unroll
    for (int r = 0; r < 4; r++) {
        float sm = head_sum16(x[0][r] + x[1][r] + x[2][r] + x[3][r]);
        float mu = sm * 0.015625f;
        float vv = 0.f;
#pragma unroll
        for (int nt = 0; nt < 4; nt++) { float dd = x[nt][r] - mu; vv = fmaf(dd, dd, vv); }
        vv = head_sum16(vv);
        float rs = rsqrtf(vv * 0.015625f + 1e-5f);
#pragma unroll
        for (int nt = 0; nt < 4; nt++) t[nt][r] = (x[nt][r] - mu) * rs * lw2[nt] + lb2[nt];
    }

    int eloc = w * 4 + lh, ge = base + eloc;

    if (base < E) {
#pragma unroll
        for (int nt = 0; nt < 4; nt++)
#pragma unroll
            for (int r = 0; r < 4; r++)
                sA[(w * 16 + lh * 4 + r) * 72 + nt * 16 + l15] = f2bf(t[nt][r]);
        const bf16x8_t* bpc = (const bf16x8_t*)W.WcP;
        f32x4_t ca = {0.f,0.f,0.f,0.f};
#pragma unroll
        for (int kstep = 0; kstep < 2; kstep++) {
            bf16x8_t a = *(const bf16x8_t*)&sA[arow + kstep * 32 + kof];
            ca = MFMA(a, bpc[kstep * 64 + lane], ca);
        }
        if (l15 < 4 && ge < E) {
            float bcv = W.bc[l15];
#pragma unroll
            for (int r = 0; r < 4; r++)
                cat_out[((size_t)r * E + ge) * 4 + l15] = ca[r] + bcv;
        }
    }

    if (ge < M) {
#pragma unroll
        for (int nt = 0; nt < 4; nt++)
            mem_out[(size_t)ge * 64 + nt * 16 + l15] = t[nt][0] + t[nt][1] + t[nt][2] + t[nt][3];
    }
}

// ---------------- hypernetwork bilinear v7.1 "P-scheme": 128 rows/block,
// 2-i chunks, double-buffered, SINGLE barrier per chunk:
//   vmcnt(0) -> barrier -> stage(c+1 -> buf^1) -> compute(c, buf).
// vmcnt(0) waits loads issued one full compute-phase (~900cyc) earlier; the
// barrier both publishes chunk c and licenses overwriting buf^1.
__global__ __launch_bounds__(256, 3) void k_hyper(
        const float* __restrict__ feat, const int* __restrict__ src_idx,
        const int* __restrict__ dst_idx, const float* __restrict__ memall,
        const short* __restrict__ Bpack,
        float* __restrict__ agg, float* __restrict__ selfm, int E, int M)
{
    __shared__ short xsT[64 * 132];                 // bf16 x^T: [i][row] (wave-private rows)
    __shared__ __align__(16) short sB[2][8192];     // 2 x 16KB: 2-i B-frag chunks
    int tid = threadIdx.x, lane = tid & 63, w = tid >> 6;
    int l15 = lane & 15, lh = lane >> 4, koff = lh * 8;
    int base = blockIdx.x * 128;

    const bf16x8_t* bp = (const bf16x8_t*)Bpack;

    auto stage = [&](int c, int buf) {
#pragma unroll
        for (int jj = 0; jj < 4; ++jj) {
            int j = w * 4 + jj;
            int il_ic = j >> 3, q = j & 7;
            const short* src = (const short*)(bp + (size_t)(c * 2 + il_ic) * 512
                                              + (q >> 2) * 256 + (q & 3) * 64 + lane);
            short* dst = &sB[buf][j * 512];
            __builtin_amdgcn_global_load_lds(
                (const __attribute__((address_space(1))) void*)src,
                (__attribute__((address_space(3))) void*)dst, 16, 0, 0);
        }
    };

    stage(0, 0);

    for (int rr = 0; rr < 32; ++rr) {
        int row = w * 32 + rr, gr = base + row;
        float xv = 0.f;
        if (gr < M) {
            int xi = gr < E ? src_idx[gr] : gr - E;
            xv = feat[(size_t)xi * 64 + lane];
        }
        xsT[lane * 132 + row] = f2bf(xv);
    }

    bf16x8_t am[2][2];
#pragma unroll
    for (int tt = 0; tt < 2; ++tt) {
        int gr = base + w * 32 + tt * 16 + l15;
        const float* mp = memall + (size_t)(gr < M ? gr : 0) * 64 + koff;
#pragma unroll
        for (int kk = 0; kk < 2; ++kk)
#pragma unroll
            for (int t = 0; t < 8; ++t)
                am[tt][kk][t] = f2bf(mp[kk * 32 + t]);
    }

    f32x4_t out[2][4];
#pragma unroll
    for (int tt = 0; tt < 2; ++tt)
#pragma unroll
        for (int nt = 0; nt < 4; ++nt) out[tt][nt] = (f32x4_t){0.f, 0.f, 0.f, 0.f};
    const f32x4_t ZERO = {0.f, 0.f, 0.f, 0.f};

    int xrow0 = w * 32 + lh * 4;

    int cur = 0;
    for (int c = 0; c < 32; ++c) {
        asm volatile("s_waitcnt vmcnt(0)" ::: "memory");   // chunk c landed (issued 1 chunk ago)
        __builtin_amdgcn_s_barrier();                      // publish c; buf^1 free to overwrite
        if (c + 1 < 32) stage(c + 1, cur ^ 1);
#pragma unroll
        for (int ic = 0; ic < 2; ++ic) {
            int i = c * 2 + ic;
            unsigned long long xw0 = *(const unsigned long long*)&xsT[i * 132 + xrow0];
            unsigned long long xw1 = *(const unsigned long long*)&xsT[i * 132 + xrow0 + 16];
            float x0[4], x1[4];
            {
                unsigned lo0 = (unsigned)xw0, hi0 = (unsigned)(xw0 >> 32);
                unsigned lo1 = (unsigned)xw1, hi1 = (unsigned)(xw1 >> 32);
                x0[0] = __builtin_bit_cast(float, lo0 << 16);
                x0[1] = __builtin_bit_cast(float, lo0 & 0xffff0000u);
                x0[2] = __builtin_bit_cast(float, hi0 << 16);
                x0[3] = __builtin_bit_cast(float, hi0 & 0xffff0000u);
                x1[0] = __builtin_bit_cast(float, lo1 << 16);
                x1[1] = __builtin_bit_cast(float, lo1 & 0xffff0000u);
                x1[2] = __builtin_bit_cast(float, hi1 << 16);
                x1[3] = __builtin_bit_cast(float, hi1 & 0xffff0000u);
            }
            const bf16x8_t* bfr = (const bf16x8_t*)&sB[cur][ic * 4096];
            f32x4_t P0[4], P1[4];
            __builtin_amdgcn_s_setprio(1);
#pragma unroll
            for (int nt = 0; nt < 4; ++nt) {
                bf16x8_t B0 = bfr[nt * 64 + lane];
                bf16x8_t B1 = bfr[(4 + nt) * 64 + lane];
                P0[nt] = MFMA(am[0][0], B0, ZERO);
                P1[nt] = MFMA(am[1][0], B0, ZERO);
                P0[nt] = MFMA(am[0][1], B1, P0[nt]);
                P1[nt] = MFMA(am[1][1], B1, P1[nt]);
            }
            __builtin_amdgcn_s_setprio(0);
#pragma unroll
            for (int nt = 0; nt < 4; ++nt)
#pragma unroll
                for (int r = 0; r < 4; ++r) {
                    out[0][nt][r] = fmaf(x0[r], P0[nt][r], out[0][nt][r]);
                    out[1][nt][r] = fmaf(x1[r], P1[nt][r], out[1][nt][r]);
                }
        }
        cur ^= 1;
    }

#pragma unroll
    for (int tt = 0; tt < 2; ++tt) {
        int orow = w * 32 + tt * 16 + lh * 4;
        int di[4];
#pragma unroll
        for (int r = 0; r < 4; ++r) {
            int grow = base + orow + r;
            di[r] = (grow < E) ? dst_idx[grow] : 0;
        }
#pragma unroll
        for (int nt = 0; nt < 4; ++nt) {
            int o = nt * 16 + l15;
#pragma unroll
            for (int r = 0; r < 4; ++r) {
                int grow = base + orow + r;
                if (grow < M) {
                    float v = out[tt][nt][r];
                    if (grow < E) atomicAdd(&agg[(size_t)di[r] * 64 + o], v);
                    else selfm[(size_t)(grow - E) * 64 + o] = v;
                }
            }
        }
    }
}

// ---------------- finalize + scatter merged: blocks [0,FB) fin, [FB,FB+NCH) scatter
__global__ __launch_bounds__(256) void k_finsc(
        const float* __restrict__ agg, const int* __restrict__ cnt,
        const float* __restrict__ selfm, const float* __restrict__ h_bias,
        float* __restrict__ outp, int N,
        const int* __restrict__ etype, const float* __restrict__ cat_all,
        const int* __restrict__ chunkoff, const int* __restrict__ startg,
        const int* __restrict__ countsg,
        float* __restrict__ out_label, float* __restrict__ out_cat, int E, int FB)
{
    if ((int)blockIdx.x < FB) {
        int t = blockIdx.x * 256 + threadIdx.x;
        if (t < N * 64) {
            int n = t >> 6, o = t & 63;
            int c = cnt[n];
            float av = (c > 0) ? agg[t] / (float)c : 0.f;
            outp[t] = av + h_bias[o] + selfm[t];
        }
    } else {
        __shared__ int wc[4][8];
        int tid = threadIdx.x, lane = tid & 63, w = tid >> 6;
        int chunk = blockIdx.x - FB;
        int e = chunk * 256 + w * 64 + lane;
        int et = (e < E) ? etype[e] : -1;
        unsigned long long mk[8];
#pragma unroll
        for (int g = 0; g < 8; g++) mk[g] = __ballot(et == g);
        if (lane < 8) wc[w][lane] = (int)__popcll(mk[lane]);
        __syncthreads();
        if (et >= 0) {
            unsigned long long lt = (1ull << lane) - 1ull;
            int myr = chunkoff[chunk * 8 + et] + (int)__popcll(mk[et] & lt);
#pragma unroll
            for (int w2 = 0; w2 < 4; w2++) if (w2 < w) myr += wc[w2][et];
            int sg = startg[et], cg = countsg[et];
            size_t pbase = (size_t)sg * 4 + myr;
#pragma unroll
            for (int i = 0; i < 4; i++) {
                size_t pos = pbase + (size_t)i * cg;
                out_label[pos] = (float)i;
                const float* ca = &cat_all[((size_t)i * E + e) * 4];
                float4 cv = {ca[0], ca[1], ca[2], ca[3]};
                *(float4*)&out_cat[pos * 4] = cv;
            }
        }
    }
}

extern "C" void kernel_launch(void* const* d_in, const int* in_sizes, int n_in,
                              void* d_out, int out_size, void* d_ws, size_t ws_size,
                              hipStream_t stream)
{
    const float* feat    = (const float*)d_in[0];
    const int*   src_idx = (const int*)d_in[1];
    const int*   dst_idx = (const int*)d_in[2];
    const int*   etype   = (const int*)d_in[3];
    const float* Wqkv    = (const float*)d_in[4];
    const float* bqkv    = (const float*)d_in[5];
    const float* Wo      = (const float*)d_in[6];
    const float* bo      = (const float*)d_in[7];
    const float* W1      = (const float*)d_in[8];
    const float* b1      = (const float*)d_in[9];
    const float* W2      = (const float*)d_in[10];
    const float* b2      = (const float*)d_in[11];
    const float* ln1w    = (const float*)d_in[12];
    const float* ln1b    = (const float*)d_in[13];
    const float* ln2w    = (const float*)d_in[14];
    const float* ln2b    = (const float*)d_in[15];
    const float* Wc      = (const float*)d_in[16];
    const float* bc      = (const float*)d_in[17];
    const float* CLS     = (const float*)d_in[18];
    const float* SEP     = (const float*)d_in[19];
    const float* Wm      = (const float*)d_in[20];
    const float* h_bias  = (const float*)d_in[21];

    const int N = in_sizes[0] / 64;
    const int E = in_sizes[1];
    const int M = E + N;                 // total hyper/encoder units
    const int NCH = (E + 255) / 256;
    const int FB = (N * 64 + 255) / 256;
    const int KB = (N + 63) / 64;

    float* ws = (float*)d_ws;
    size_t off = 0;
    auto alloc = [&](size_t n) { float* p = ws + off; off += (n + 63) & ~(size_t)63; return p; };
    float* qs      = alloc((size_t)N * 16);          // per-node attention scores [N][h*4+i]
    float* vnode   = alloc((size_t)N * 64);
    float* mem_all = alloc((size_t)M * 64);          // [0,E) edge, [E,M) self
    float* cat_all = alloc((size_t)E * 16);
    float* agg     = alloc((size_t)N * 64 + N);      // agg + cnt contiguous for one memset
    int*   cnt     = (int*)(agg + (size_t)N * 64);
    float* selfm   = alloc((size_t)N * 64);
    float* consts  = alloc(1024);
    short* Bpack   = (short*)alloc(131072);          // 262144 bf16
    short* WoP     = (short*)alloc(2048);
    short* WkvP    = (short*)alloc(4096);
    short* W1P     = (short*)alloc(512);
    short* W2P     = (short*)alloc(1024);
    short* WcP     = (short*)alloc(512);
    short* WqkP    = (short*)alloc(512);             // 1024 bf16
    float* bqk     = alloc(64);
    int*   hist    = (int*)alloc(NCH * 8);
    int*   chunkoff= (int*)alloc(NCH * 8);
    int*   startg  = (int*)alloc(8);
    int*   countsg = (int*)alloc(8);

    float* out_node  = (float*)d_out;
    float* out_label = out_node + (size_t)N * 64;
    float* out_cat   = out_label + (size_t)4 * E;

    hipMemsetAsync(agg, 0, ((size_t)N * 64 + N) * sizeof(float), stream);

    k_prep<<<138 + NCH, 256, 0, stream>>>(Wo, Wqkv, W1, W2, Wm, Wc, bqkv, CLS, SEP,
                                          etype, dst_idx, Bpack, WoP, WkvP, W1P, W2P, WcP,
                                          consts, WqkP, bqk, hist, cnt, E);

    k_kv<<<KB + 1, 256, 0, stream>>>(feat, WkvP, WqkP, bqkv, bqk, vnode, qs, N,
                                     hist, chunkoff, startg, countsg, NCH, KB);

    EncW W{consts, CLS, bo, b1, b2, ln1w, ln1b, ln2w, ln2b, WoP, W1P, W2P, WcP, bc};

    k_enc<<<(M + 15) / 16, 256, 0, stream>>>(src_idx, dst_idx, vnode, qs, W,
                                             mem_all, cat_all, E, M);

    k_hyper<<<(M + 127) / 128, 256, 0, stream>>>(feat, src_idx, dst_idx, mem_all, Bpack,
                                                 agg, selfm, E, M);

    k_finsc<<<FB + NCH, 256, 0, stream>>>(agg, cnt, selfm, h_bias, out_node, N,
                                          etype, cat_all, chunkoff, startg, countsg,
                                          out_label, out_cat, E, FB);
}